// Round 3
// baseline (5154.549 us; speedup 1.0000x reference)
//
#include <hip/hip_runtime.h>
#include <hip/hip_bf16.h>

#define B_ 2
#define S_ 2048
#define DM 1024
#define DI 2048
#define DSTATE 16
#define DTR 64
#define KC 4
#define DFF 4096
#define EPSF 1e-6f

#define CONV_OFF (B_*S_*DM)                 // 4,194,304
#define SSM_OFF  (CONV_OFF + B_*DI*KC)      // +16,384

__device__ __forceinline__ float siluf(float x){ return x / (1.f + __expf(-x)); }
__device__ __forceinline__ float softplusf(float x){
  return (x > 0.f) ? (x + log1pf(__expf(-x))) : log1pf(__expf(x));
}

// ---------------- RMSNorm over last dim (D=1024), one block per row ----------------
__global__ __launch_bounds__(256) void k_rms(const float* __restrict__ in,
    const float* __restrict__ w, float* __restrict__ out) {
  int t = blockIdx.x, tid = threadIdx.x;
  const int base = t * DM;
  float v[4]; float ss = 0.f;
  #pragma unroll
  for (int i = 0; i < 4; ++i) {
    float x = in[base + tid + i*256];
    v[i] = x; ss += x * x;
  }
  #pragma unroll
  for (int m = 1; m < 64; m <<= 1) ss += __shfl_xor(ss, m, 64);
  __shared__ float sred[4];
  if ((tid & 63) == 0) sred[tid >> 6] = ss;
  __syncthreads();
  float tot = sred[0] + sred[1] + sred[2] + sred[3];
  float r = rsqrtf(tot * (1.f / DM) + EPSF);
  #pragma unroll
  for (int i = 0; i < 4; ++i)
    out[base + tid + i*256] = v[i] * r * w[tid + i*256];
}

// ---------------- Generic f32 SGEMM: A(MxK) * B(KxN), f32 accumulate --------------
// MODE 0: OutF = acc
// MODE 1: OutF = acc + Res
// MODE 2: OutF = silu(acc) * acc2   (B2 used)
template<int MODE>
__global__ __launch_bounds__(256) void k_sgemm(
    const float* __restrict__ A, const float* __restrict__ Bw,
    const float* __restrict__ Bw2, const float* __restrict__ Res,
    float* __restrict__ OutF, int M, int N, int K)
{
  __shared__ float As[16][65];
  __shared__ float Bs[16][64];
  __shared__ float Bs2[16][64];
  int tid = threadIdx.x;
  int tn0 = blockIdx.x * 64, tm0 = blockIdx.y * 64;
  int m0 = (tid >> 4) * 4, n0 = (tid & 15) * 4;
  float acc[4][4] = {}; float acc2[4][4] = {};
  for (int k0 = 0; k0 < K; k0 += 16) {
    #pragma unroll
    for (int i = 0; i < 4; ++i) {
      int idx = tid + i*256;
      int r = idx >> 4, c = idx & 15;
      As[c][r] = A[(tm0 + r)*K + k0 + c];
      int rb = idx >> 6, cb = idx & 63;
      int gc = tn0 + cb;
      float bv = 0.f, bv2 = 0.f;
      if (gc < N) {
        bv = Bw[(k0 + rb)*N + gc];
        if (MODE == 2) bv2 = Bw2[(k0 + rb)*N + gc];
      }
      Bs[rb][cb] = bv;
      if (MODE == 2) Bs2[rb][cb] = bv2;
    }
    __syncthreads();
    #pragma unroll
    for (int k = 0; k < 16; ++k) {
      float a[4], bv[4], b2[4];
      #pragma unroll
      for (int i = 0; i < 4; ++i) a[i] = As[k][m0 + i];
      #pragma unroll
      for (int j = 0; j < 4; ++j) {
        bv[j] = Bs[k][n0 + j];
        if (MODE == 2) b2[j] = Bs2[k][n0 + j];
      }
      #pragma unroll
      for (int i = 0; i < 4; ++i)
        #pragma unroll
        for (int j = 0; j < 4; ++j) {
          acc[i][j] += a[i] * bv[j];
          if (MODE == 2) acc2[i][j] += a[i] * b2[j];
        }
    }
    __syncthreads();
  }
  #pragma unroll
  for (int i = 0; i < 4; ++i) {
    int r = tm0 + m0 + i;
    #pragma unroll
    for (int j = 0; j < 4; ++j) {
      int c = tn0 + n0 + j;
      if (c < N) {
        int idx = r*N + c;
        if (MODE == 0) OutF[idx] = acc[i][j];
        else if (MODE == 1) OutF[idx] = acc[i][j] + Res[idx];
        else OutF[idx] = siluf(acc[i][j]) * acc2[i][j];
      }
    }
  }
}

// ---------------- depthwise causal conv (K=4) + bias + silu (per-batch) -----------
__global__ __launch_bounds__(256) void k_conv(const float* __restrict__ XZ,
    const float* __restrict__ cw, const float* __restrict__ cb,
    float* __restrict__ XC) {
  int i = blockIdx.x * 256 + threadIdx.x;        // i = s*DI + d
  int d = i & (DI - 1);
  int s = i >> 11;
  float acc = cb[d];
  #pragma unroll
  for (int k = 0; k < KC; ++k) {
    int s2 = s - (KC - 1) + k;
    if (s2 >= 0) acc += XZ[s2*(2*DI) + d] * cw[d*KC + k];
  }
  XC[i] = siluf(acc);
}

// ---------------- conv_state output (per-batch): x_pre[S-4+k, d] -> (d,k) ---------
__global__ __launch_bounds__(256) void k_convstate(const float* __restrict__ XZ,
    float* __restrict__ outF, int b) {
  int i = blockIdx.x * 256 + threadIdx.x;        // i = d*KC + k, < 8192
  int k = i & 3;
  int d = i >> 2;
  outF[CONV_OFF + b*DI*KC + i] = XZ[(S_ - KC + k)*(2*DI) + d];
}

// ---------------- per-token small RMSNorms (dt 64, B 16, C 16) --------------------
__global__ __launch_bounds__(64) void k_norms(const float* __restrict__ PROJ,
    const float* __restrict__ dtw, const float* __restrict__ bw,
    const float* __restrict__ cw, float* __restrict__ NDT,
    float* __restrict__ BC) {
  int t = blockIdx.x, lane = threadIdx.x;
  float v = PROJ[t*96 + lane];
  float ss = v * v;
  #pragma unroll
  for (int m = 1; m < 64; m <<= 1) ss += __shfl_xor(ss, m, 64);
  float r = rsqrtf(ss * (1.f / DTR) + EPSF);
  NDT[t*DTR + lane] = v * r * dtw[lane];
  if (lane < 32) {
    float u = PROJ[t*96 + 64 + lane];
    float s2 = u * u;
    #pragma unroll
    for (int m = 1; m < 16; m <<= 1) s2 += __shfl_xor(s2, m, 16);
    float r2 = rsqrtf(s2 * (1.f / DSTATE) + EPSF);
    float wv = (lane < 16) ? bw[lane] : cw[lane - 16];
    BC[t*32 + lane] = u * r2 * wv;
  }
}

// ---------------- dt projection: (S x 64) @ (64 x DI) + bias, softplus ------------
__global__ __launch_bounds__(256) void k_dtproj(const float* __restrict__ NDT,
    const float* __restrict__ W, const float* __restrict__ bias,
    float* __restrict__ DT) {
  __shared__ float nd[16][64];
  int tid = threadIdx.x;
  int d = blockIdx.x * 256 + tid;
  int t0 = blockIdx.y * 16;
  #pragma unroll
  for (int i = 0; i < 4; ++i) {
    int idx = tid + i*256;
    nd[idx >> 6][idx & 63] = NDT[(t0 + (idx >> 6))*DTR + (idx & 63)];
  }
  __syncthreads();
  float acc[16] = {};
  for (int k = 0; k < 64; ++k) {
    float wv = W[k*DI + d];
    #pragma unroll
    for (int tk = 0; tk < 16; ++tk) acc[tk] += nd[tk][k] * wv;
  }
  float bv = bias[d];
  #pragma unroll
  for (int tk = 0; tk < 16; ++tk)
    DT[(t0 + tk)*DI + d] = softplusf(acc[tk] + bv);
}

// ---------------- sequential SSM scan (per-batch): thread per (d,n) ---------------
// NOTE: Y aliases XC (same wave reads XC[t,d] before lane n==0 writes Y[t,d];
// lockstep within a wave makes this safe). No __restrict__ on XC/Y.
__global__ __launch_bounds__(256) void k_scan(const float* __restrict__ DT,
    const float* XC, const float* __restrict__ BC,
    const float* __restrict__ A_log, const float* __restrict__ Dskip,
    float* Y, float* __restrict__ outF, int b) {
  int g = blockIdx.x * 256 + threadIdx.x;   // (d, n)
  int n = g & 15;
  int d = g >> 4;
  float A = -__expf(A_log[d*DSTATE + n]);
  float Dd = Dskip[d];
  float h = 0.f;
  #pragma unroll 2
  for (int t = 0; t < S_; ++t) {
    float dtv = DT[t*DI + d];
    float xv  = XC[t*DI + d];
    float Bn  = BC[t*32 + n];
    float Cn  = BC[t*32 + 16 + n];
    float dA = __expf(dtv * A);
    h = h * dA + dtv * xv * Bn;
    float p = h * Cn;
    p += __shfl_xor(p, 1, 16);
    p += __shfl_xor(p, 2, 16);
    p += __shfl_xor(p, 4, 16);
    p += __shfl_xor(p, 8, 16);
    if (n == 0) Y[t*DI + d] = p + Dd * xv;
  }
  outF[SSM_OFF + b*DI*DSTATE + d*DSTATE + n] = h;
}

// ---------------- y *= silu(z) ----------------------------------------------------
__global__ __launch_bounds__(256) void k_ymul(float* Y, const float* __restrict__ XZ) {
  int i = blockIdx.x * 256 + threadIdx.x;  // s*DI + d
  int d = i & (DI - 1);
  int s = i >> 11;
  float z = XZ[s*(2*DI) + DI + d];
  Y[i] = Y[i] * siluf(z);
}

extern "C" void kernel_launch(void* const* d_in, const int* in_sizes, int n_in,
                              void* d_out, int out_size, void* d_ws, size_t ws_size,
                              hipStream_t stream) {
  const float* hs         = (const float*)d_in[0];
  const float* in_proj_w  = (const float*)d_in[1];
  const float* conv_w     = (const float*)d_in[2];
  const float* conv_b     = (const float*)d_in[3];
  const float* x_proj_w   = (const float*)d_in[4];
  const float* dt_proj_w  = (const float*)d_in[5];
  const float* dt_proj_b  = (const float*)d_in[6];
  const float* dt_ln_w    = (const float*)d_in[7];
  const float* b_ln_w     = (const float*)d_in[8];
  const float* c_ln_w     = (const float*)d_in[9];
  const float* A_log      = (const float*)d_in[10];
  const float* D_skip     = (const float*)d_in[11];
  const float* out_proj_w = (const float*)d_in[12];
  const float* input_ln_w = (const float*)d_in[13];
  const float* pre_moe_ln = (const float*)d_in[14];
  const float* gate_w     = (const float*)d_in[15];
  const float* up_w       = (const float*)d_in[16];
  const float* down_w     = (const float*)d_in[17];
  float* outF = (float*)d_out;

  // ---- per-batch f32 workspace (reused for b=0,1): ~83 MB ----
  float* XZf  = (float*)d_ws;                   // S*2*DI   (32 MB; also FFN act)
  float* XCf  = XZf  + (size_t)S_*2*DI;         // S*DI     (16 MB; also Y)
  float* DTf  = XCf  + (size_t)S_*DI;           // S*DI     (16 MB)
  float* HNf  = DTf  + (size_t)S_*DI;           // S*DM     (8 MB)
  float* HIDf = HNf  + (size_t)S_*DM;           // S*DM     (8 MB)
  float* PROJ = HIDf + (size_t)S_*DM;           // S*96
  float* NDT  = PROJ + (size_t)S_*96;           // S*64
  float* BC   = NDT  + (size_t)S_*DTR;          // S*32

  for (int b = 0; b < B_; ++b) {
    const float* hs_b  = hs   + (size_t)b*S_*DM;
    float*       out_b = outF + (size_t)b*S_*DM;

    // 1. input RMSNorm
    k_rms<<<S_, 256, 0, stream>>>(hs_b, input_ln_w, HNf);
    // 2. in_proj: xz = h @ W  (2048x1024 @ 1024x4096)
    k_sgemm<0><<<dim3(64, 32), 256, 0, stream>>>(HNf, in_proj_w, nullptr, nullptr, XZf, S_, 2*DI, DM);
    // 3. depthwise causal conv + silu
    k_conv<<<(S_*DI)/256, 256, 0, stream>>>(XZf, conv_w, conv_b, XCf);
    // 3b. conv_state output
    k_convstate<<<(DI*KC)/256, 256, 0, stream>>>(XZf, outF, b);
    // 4. x_proj: proj = x @ W (2048x2048 @ 2048x96)
    k_sgemm<0><<<dim3(2, 32), 256, 0, stream>>>(XCf, x_proj_w, nullptr, nullptr, PROJ, S_, 96, DI);
    // 5. small RMSNorms (dt / B / C)
    k_norms<<<S_, 64, 0, stream>>>(PROJ, dt_ln_w, b_ln_w, c_ln_w, NDT, BC);
    // 6. dt projection + softplus
    k_dtproj<<<dim3(DI/256, S_/16), 256, 0, stream>>>(NDT, dt_proj_w, dt_proj_b, DTf);
    // 7. SSM scan (+ D_skip fused, ssm_state output); Y aliases XCf
    k_scan<<<(DI*DSTATE)/256, 256, 0, stream>>>(DTf, XCf, BC, A_log, D_skip, XCf, outF, b);
    // 8. y *= silu(z)   (Y == XCf)
    k_ymul<<<(S_*DI)/256, 256, 0, stream>>>(XCf, XZf);
    // 9. out_proj + residual add -> HIDf
    k_sgemm<1><<<dim3(16, 32), 256, 0, stream>>>(XCf, out_proj_w, nullptr, hs_b, HIDf, S_, DM, DI);
    // 10. pre-MoE RMSNorm
    k_rms<<<S_, 256, 0, stream>>>(HIDf, pre_moe_ln, HNf);
    // 11. gate/up fused GEMM -> FF (reuse XZf)
    k_sgemm<2><<<dim3(64, 32), 256, 0, stream>>>(HNf, gate_w, up_w, nullptr, XZf, S_, DFF, DM);
    // 12. down GEMM + residual -> out
    k_sgemm<1><<<dim3(16, 32), 256, 0, stream>>>(XZf, down_w, nullptr, HIDf, out_b, S_, DM, DFF);
  }
}

// Round 4
// 1566.690 us; speedup vs baseline: 3.2901x; 3.2901x over previous
//
#include <hip/hip_runtime.h>
#include <hip/hip_bf16.h>

#define B_ 2
#define S_ 2048
#define DM 1024
#define DI 2048
#define DSTATE 16
#define DTR 64
#define KC 4
#define DFF 4096
#define EPSF 1e-6f
#define NC 8
#define LCH (S_/NC)

#define CONV_OFF (B_*S_*DM)
#define SSM_OFF  (CONV_OFF + B_*DI*KC)

typedef __attribute__((ext_vector_type(8))) short short8;
typedef __attribute__((ext_vector_type(4))) float f32x4;

__device__ __forceinline__ float siluf(float x){ return x / (1.f + __expf(-x)); }
__device__ __forceinline__ float softplusf(float x){
  return (x > 0.f) ? (x + log1pf(__expf(-x))) : log1pf(__expf(x));
}
__device__ __forceinline__ float us2f(ushort u){
  union { float f; unsigned u32; } v; v.u32 = ((unsigned)u) << 16; return v.f;
}
__device__ __forceinline__ ushort f2us(float f){
  __hip_bfloat16 h = __float2bfloat16(f);  // RTN
  return *reinterpret_cast<ushort*>(&h);
}

// ---------------- weight convert+transpose: W f32 [K][N] -> WT bf16 [N][K] --------
__global__ __launch_bounds__(256) void k_wt(const float* __restrict__ W,
    ushort* __restrict__ WT, int K, int N) {
  __shared__ float t[32][33];
  int n0 = blockIdx.x * 32, k0 = blockIdx.y * 32;
  int tx = threadIdx.x & 31, ty = threadIdx.x >> 5;   // 32 x 8
  #pragma unroll
  for (int i = 0; i < 4; ++i) t[ty + i*8][tx] = W[(size_t)(k0 + ty + i*8)*N + n0 + tx];
  __syncthreads();
  #pragma unroll
  for (int i = 0; i < 4; ++i)
    WT[(size_t)(n0 + ty + i*8)*K + k0 + tx] = f2us(t[tx][ty + i*8]);
}

// ---------------- RMSNorm (D=1024), f32 in -> bf16 out ---------------------------
__global__ __launch_bounds__(256) void k_rms(const float* __restrict__ in,
    const float* __restrict__ w, ushort* __restrict__ out) {
  int t = blockIdx.x, tid = threadIdx.x;
  const int base = t * DM;
  float v[4]; float ss = 0.f;
  #pragma unroll
  for (int i = 0; i < 4; ++i) {
    float x = in[base + tid + i*256];
    v[i] = x; ss += x * x;
  }
  #pragma unroll
  for (int m = 1; m < 64; m <<= 1) ss += __shfl_xor(ss, m, 64);
  __shared__ float sred[4];
  if ((tid & 63) == 0) sred[tid >> 6] = ss;
  __syncthreads();
  float tot = sred[0] + sred[1] + sred[2] + sred[3];
  float r = rsqrtf(tot * (1.f / DM) + EPSF);
  #pragma unroll
  for (int i = 0; i < 4; ++i)
    out[base + tid + i*256] = f2us(v[i] * r * w[tid + i*256]);
}

// ---------------- MFMA GEMM: A[M][K] bf16 * WT[N][K] bf16, 128x128 tile ----------
// MODE 0 (XZ):     n<DI -> XZx f32 ; n>=DI -> Z bf16      (in_proj)
// MODE 1 (ADD):    outF = acc + Res(f32)                  (out_proj / down)
// MODE 2 (GATEUP): FF = bf16(silu(acc)*acc2)              (dual-B)
template<int MODE>
__global__ __launch_bounds__(256) void k_mfma(
    const ushort* __restrict__ Ag, const ushort* __restrict__ B1,
    const ushort* __restrict__ B2, const float* __restrict__ Res,
    float* __restrict__ XZx, ushort* __restrict__ outU,
    float* __restrict__ outF, int M, int N, int K)
{
  __shared__ ushort As[128*40];
  __shared__ ushort Bs[128*40];
  __shared__ ushort Bs2[(MODE == 2) ? 128*40 : 8];
  int tid = threadIdx.x;
  int gn0 = blockIdx.x * 128, gm0 = blockIdx.y * 128;
  int wid = tid >> 6, lane = tid & 63;
  int mo = (wid >> 1) * 64, no = (wid & 1) * 64;
  int lr = lane & 15, lk = lane >> 4;

  f32x4 acc[4][4];
  f32x4 acc2[(MODE == 2) ? 4 : 1][(MODE == 2) ? 4 : 1];
  #pragma unroll
  for (int i = 0; i < 4; ++i)
    #pragma unroll
    for (int j = 0; j < 4; ++j) {
      acc[i][j] = (f32x4){0.f,0.f,0.f,0.f};
      if (MODE == 2) acc2[i][j] = (f32x4){0.f,0.f,0.f,0.f};
    }

  for (int k0 = 0; k0 < K; k0 += 32) {
    #pragma unroll
    for (int i = 0; i < 2; ++i) {
      int chunk = tid + i*256;
      int row = chunk >> 2, co = chunk & 3;
      *(short8*)&As[row*40 + co*8] =
          *(const short8*)(Ag + (size_t)(gm0 + row)*K + k0 + co*8);
      *(short8*)&Bs[row*40 + co*8] =
          *(const short8*)(B1 + (size_t)(gn0 + row)*K + k0 + co*8);
      if (MODE == 2)
        *(short8*)&Bs2[row*40 + co*8] =
            *(const short8*)(B2 + (size_t)(gn0 + row)*K + k0 + co*8);
    }
    __syncthreads();
    short8 af[4], bfr[4], bfr2[4];
    #pragma unroll
    for (int mi = 0; mi < 4; ++mi)
      af[mi] = *(const short8*)&As[(mo + mi*16 + lr)*40 + lk*8];
    #pragma unroll
    for (int ni = 0; ni < 4; ++ni) {
      bfr[ni] = *(const short8*)&Bs[(no + ni*16 + lr)*40 + lk*8];
      if (MODE == 2) bfr2[ni] = *(const short8*)&Bs2[(no + ni*16 + lr)*40 + lk*8];
    }
    #pragma unroll
    for (int mi = 0; mi < 4; ++mi)
      #pragma unroll
      for (int ni = 0; ni < 4; ++ni) {
        acc[mi][ni] = __builtin_amdgcn_mfma_f32_16x16x32_bf16(af[mi], bfr[ni], acc[mi][ni], 0, 0, 0);
        if (MODE == 2)
          acc2[mi][ni] = __builtin_amdgcn_mfma_f32_16x16x32_bf16(af[mi], bfr2[ni], acc2[mi][ni], 0, 0, 0);
      }
    __syncthreads();
  }

  #pragma unroll
  for (int mi = 0; mi < 4; ++mi)
    #pragma unroll
    for (int ni = 0; ni < 4; ++ni)
      #pragma unroll
      for (int r = 0; r < 4; ++r) {
        int gr = gm0 + mo + mi*16 + lk*4 + r;
        int gc = gn0 + no + ni*16 + lr;
        float v = acc[mi][ni][r];
        size_t idx = (size_t)gr*N + gc;
        if (MODE == 0) {
          if (gc < DI) XZx[(size_t)gr*DI + gc] = v;
          else         outU[(size_t)gr*DI + gc - DI] = f2us(v);
        } else if (MODE == 1) {
          outF[idx] = v + Res[idx];
        } else {
          outU[idx] = f2us(siluf(v) * acc2[mi][ni][r]);
        }
      }
}

// ---------------- x_proj SGEMM: A bf16 [M][K] * B f32 [K][96] -> PROJ f32 --------
__global__ __launch_bounds__(256) void k_sgemm_x(
    const ushort* __restrict__ A, const float* __restrict__ Bw,
    float* __restrict__ OutF, int M, int N, int K)
{
  __shared__ float As[16][65];
  __shared__ float Bsh[16][64];
  int tid = threadIdx.x;
  int tn0 = blockIdx.x * 64, tm0 = blockIdx.y * 64;
  int m0 = (tid >> 4) * 4, n0 = (tid & 15) * 4;
  float acc[4][4] = {};
  for (int k0 = 0; k0 < K; k0 += 16) {
    #pragma unroll
    for (int i = 0; i < 4; ++i) {
      int idx = tid + i*256;
      int r = idx >> 4, c = idx & 15;
      As[c][r] = us2f(A[(size_t)(tm0 + r)*K + k0 + c]);
      int rb = idx >> 6, cb = idx & 63;
      int gc = tn0 + cb;
      Bsh[rb][cb] = (gc < N) ? Bw[(size_t)(k0 + rb)*N + gc] : 0.f;
    }
    __syncthreads();
    #pragma unroll
    for (int k = 0; k < 16; ++k) {
      float a[4], bv[4];
      #pragma unroll
      for (int i = 0; i < 4; ++i) a[i] = As[k][m0 + i];
      #pragma unroll
      for (int j = 0; j < 4; ++j) bv[j] = Bsh[k][n0 + j];
      #pragma unroll
      for (int i = 0; i < 4; ++i)
        #pragma unroll
        for (int j = 0; j < 4; ++j) acc[i][j] += a[i] * bv[j];
    }
    __syncthreads();
  }
  #pragma unroll
  for (int i = 0; i < 4; ++i)
    #pragma unroll
    for (int j = 0; j < 4; ++j) {
      int c = tn0 + n0 + j;
      if (c < N) OutF[(size_t)(tm0 + m0 + i)*N + c] = acc[i][j];
    }
}

// ---------------- depthwise causal conv + bias + silu: XZx f32 -> XC bf16 --------
__global__ __launch_bounds__(256) void k_conv(const float* __restrict__ XZx,
    const float* __restrict__ cw, const float* __restrict__ cb,
    ushort* __restrict__ XC) {
  int i = blockIdx.x * 256 + threadIdx.x;        // s*DI + d
  int d = i & (DI - 1);
  int s = i >> 11;
  float acc = cb[d];
  #pragma unroll
  for (int k = 0; k < KC; ++k) {
    int s2 = s - (KC - 1) + k;
    if (s2 >= 0) acc += XZx[s2*DI + d] * cw[d*KC + k];
  }
  XC[i] = f2us(siluf(acc));
}

// ---------------- conv_state: XZx[S-4+k, d] -> out (b,d,k) f32 -------------------
__global__ __launch_bounds__(256) void k_convstate(const float* __restrict__ XZx,
    float* __restrict__ outF, int b) {
  int i = blockIdx.x * 256 + threadIdx.x;        // d*KC + k, < 8192
  int k = i & 3;
  int d = i >> 2;
  outF[CONV_OFF + b*DI*KC + i] = XZx[(S_ - KC + k)*DI + d];
}

// ---------------- per-token small RMSNorms (dt 64, B 16, C 16) -------------------
__global__ __launch_bounds__(64) void k_norms(const float* __restrict__ PROJ,
    const float* __restrict__ dtw, const float* __restrict__ bw,
    const float* __restrict__ cw, float* __restrict__ NDT,
    float* __restrict__ BC) {
  int t = blockIdx.x, lane = threadIdx.x;
  float v = PROJ[t*96 + lane];
  float ss = v * v;
  #pragma unroll
  for (int m = 1; m < 64; m <<= 1) ss += __shfl_xor(ss, m, 64);
  float r = rsqrtf(ss * (1.f / DTR) + EPSF);
  NDT[t*DTR + lane] = v * r * dtw[lane];
  if (lane < 32) {
    float u = PROJ[t*96 + 64 + lane];
    float s2 = u * u;
    #pragma unroll
    for (int m = 1; m < 16; m <<= 1) s2 += __shfl_xor(s2, m, 16);
    float r2 = rsqrtf(s2 * (1.f / DSTATE) + EPSF);
    float wv = (lane < 16) ? bw[lane] : cw[lane - 16];
    BC[t*32 + lane] = u * r2 * wv;
  }
}

// ---------------- dt projection: (S x 64) @ (64 x DI) + bias, softplus -> f32 ----
__global__ __launch_bounds__(256) void k_dtproj(const float* __restrict__ NDT,
    const float* __restrict__ W, const float* __restrict__ bias,
    float* __restrict__ DT) {
  __shared__ float nd[16][64];
  int tid = threadIdx.x;
  int d = blockIdx.x * 256 + tid;
  int t0 = blockIdx.y * 16;
  #pragma unroll
  for (int i = 0; i < 4; ++i) {
    int idx = tid + i*256;
    nd[idx >> 6][idx & 63] = NDT[(t0 + (idx >> 6))*DTR + (idx & 63)];
  }
  __syncthreads();
  float acc[16] = {};
  for (int k = 0; k < 64; ++k) {
    float wv = W[k*DI + d];
    #pragma unroll
    for (int tk = 0; tk < 16; ++tk) acc[tk] += nd[tk][k] * wv;
  }
  float bv = bias[d];
  #pragma unroll
  for (int tk = 0; tk < 16; ++tk)
    DT[(t0 + tk)*DI + d] = softplusf(acc[tk] + bv);
}

// ---------------- scan phase 1: per-chunk (prod dA, local h) ---------------------
__global__ __launch_bounds__(256) void k_scan1(const float* __restrict__ DT,
    const ushort* __restrict__ XC, const float* __restrict__ BC,
    const float* __restrict__ A_log, float* __restrict__ scA,
    float* __restrict__ scH) {
  int g = blockIdx.x * 256 + threadIdx.x;   // c*32768 + d*16 + n
  int n = g & 15, d = (g >> 4) & (DI - 1), c = g >> 15;
  float A = -__expf(A_log[d*DSTATE + n]);
  float h = 0.f, ap = 1.f;
  int t0 = c * LCH;
  for (int i = 0; i < LCH; ++i) {
    int t = t0 + i;
    float dtv = DT[t*DI + d];
    float xv  = us2f(XC[t*DI + d]);
    float Bn  = BC[t*32 + n];
    float dA = __expf(dtv * A);
    h = h * dA + dtv * xv * Bn;
    ap *= dA;
  }
  int idx = (d*DSTATE + n)*NC + c;
  scA[idx] = ap; scH[idx] = h;
}

// ---------------- scan phase 2: combine chunks; emit h_start + ssm_state ---------
__global__ __launch_bounds__(256) void k_scan2(const float* __restrict__ scA,
    const float* __restrict__ scH, float* __restrict__ scS,
    float* __restrict__ outF, int b) {
  int g = blockIdx.x * 256 + threadIdx.x;   // d*16 + n, < 32768
  int base = g * NC;
  float h = 0.f;
  #pragma unroll
  for (int c = 0; c < NC; ++c) {
    scS[base + c] = h;
    h = scA[base + c] * h + scH[base + c];
  }
  outF[SSM_OFF + b*DI*DSTATE + g] = h;
}

// ---------------- scan phase 3: replay with h_start; fused y*silu(z) -> ZY bf16 --
__global__ __launch_bounds__(256) void k_scan3(const float* __restrict__ DT,
    const ushort* __restrict__ XC, const float* __restrict__ BC,
    const float* __restrict__ A_log, const float* __restrict__ Dskip,
    const float* __restrict__ scS, ushort* ZY) {
  int g = blockIdx.x * 256 + threadIdx.x;
  int n = g & 15, d = (g >> 4) & (DI - 1), c = g >> 15;
  float A = -__expf(A_log[d*DSTATE + n]);
  float Dd = Dskip[d];
  float h = scS[(d*DSTATE + n)*NC + c];
  int t0 = c * LCH;
  for (int i = 0; i < LCH; ++i) {
    int t = t0 + i;
    float dtv = DT[t*DI + d];
    float xv  = us2f(XC[t*DI + d]);
    float Bn  = BC[t*32 + n];
    float Cn  = BC[t*32 + 16 + n];
    float dA = __expf(dtv * A);
    h = h * dA + dtv * xv * Bn;
    float p = h * Cn;
    p += __shfl_xor(p, 1, 16);
    p += __shfl_xor(p, 2, 16);
    p += __shfl_xor(p, 4, 16);
    p += __shfl_xor(p, 8, 16);
    if (n == 0) {
      float zv = us2f(ZY[t*DI + d]);          // z (read), then overwrite with y
      ZY[t*DI + d] = f2us((p + Dd * xv) * siluf(zv));
    }
  }
}

extern "C" void kernel_launch(void* const* d_in, const int* in_sizes, int n_in,
                              void* d_out, int out_size, void* d_ws, size_t ws_size,
                              hipStream_t stream) {
  const float* hs         = (const float*)d_in[0];
  const float* in_proj_w  = (const float*)d_in[1];
  const float* conv_w     = (const float*)d_in[2];
  const float* conv_b     = (const float*)d_in[3];
  const float* x_proj_w   = (const float*)d_in[4];
  const float* dt_proj_w  = (const float*)d_in[5];
  const float* dt_proj_b  = (const float*)d_in[6];
  const float* dt_ln_w    = (const float*)d_in[7];
  const float* b_ln_w     = (const float*)d_in[8];
  const float* c_ln_w     = (const float*)d_in[9];
  const float* A_log      = (const float*)d_in[10];
  const float* D_skip     = (const float*)d_in[11];
  const float* out_proj_w = (const float*)d_in[12];
  const float* input_ln_w = (const float*)d_in[13];
  const float* pre_moe_ln = (const float*)d_in[14];
  const float* gate_w     = (const float*)d_in[15];
  const float* up_w       = (const float*)d_in[16];
  const float* down_w     = (const float*)d_in[17];
  float* outF = (float*)d_out;

  // ---- workspace layout (~92.5 MB) ----
  char* p = (char*)d_ws;
  auto alloc = [&](size_t bytes) { void* r = (void*)p; p += (bytes + 255) & ~(size_t)255; return r; };
  ushort* WT_in   = (ushort*)alloc((size_t)4096*1024*2);
  ushort* WT_out  = (ushort*)alloc((size_t)1024*2048*2);
  ushort* WT_gate = (ushort*)alloc((size_t)4096*1024*2);
  ushort* WT_up   = (ushort*)alloc((size_t)4096*1024*2);
  ushort* WT_down = (ushort*)alloc((size_t)1024*4096*2);
  ushort* HN_bf   = (ushort*)alloc((size_t)S_*DM*2);
  ushort* XCbf    = (ushort*)alloc((size_t)S_*DI*2);
  ushort* ZY      = (ushort*)alloc((size_t)S_*DI*2);       // z, later y
  float*  XZx     = (float*) alloc((size_t)S_*DI*4);       // x pre-conv; later FF (bf16)
  ushort* FFbf    = (ushort*)XZx;                          // alias (16 MB each)
  float*  DT      = (float*) alloc((size_t)S_*DI*4);
  float*  PROJ    = (float*) alloc((size_t)S_*96*4);
  float*  NDT     = (float*) alloc((size_t)S_*DTR*4);
  float*  BC      = (float*) alloc((size_t)S_*32*4);
  float*  SC_A    = (float*) alloc((size_t)DI*DSTATE*NC*4);
  float*  SC_H    = (float*) alloc((size_t)DI*DSTATE*NC*4);
  float*  SC_S    = (float*) alloc((size_t)DI*DSTATE*NC*4);

  // ---- one-time weight convert+transpose to bf16 [N][K] ----
  k_wt<<<dim3(4096/32, 1024/32), 256, 0, stream>>>(in_proj_w,  WT_in,   1024, 4096);
  k_wt<<<dim3(1024/32, 2048/32), 256, 0, stream>>>(out_proj_w, WT_out,  2048, 1024);
  k_wt<<<dim3(4096/32, 1024/32), 256, 0, stream>>>(gate_w,     WT_gate, 1024, 4096);
  k_wt<<<dim3(4096/32, 1024/32), 256, 0, stream>>>(up_w,       WT_up,   1024, 4096);
  k_wt<<<dim3(1024/32, 4096/32), 256, 0, stream>>>(down_w,     WT_down, 4096, 1024);

  for (int b = 0; b < B_; ++b) {
    const float* hs_b  = hs   + (size_t)b*S_*DM;
    float*       out_b = outF + (size_t)b*S_*DM;   // holds HID (f32) then final out

    // 1. input RMSNorm -> bf16
    k_rms<<<S_, 256, 0, stream>>>(hs_b, input_ln_w, HN_bf);
    // 2. in_proj MFMA: x-half -> XZx f32, z-half -> ZY bf16
    k_mfma<0><<<dim3(32, 16), 256, 0, stream>>>(HN_bf, WT_in, nullptr, nullptr,
        XZx, ZY, nullptr, S_, 2*DI, DM);
    // 3. conv + silu -> XC bf16
    k_conv<<<(S_*DI)/256, 256, 0, stream>>>(XZx, conv_w, conv_b, XCbf);
    // 3b. conv_state (f32, exact path)
    k_convstate<<<(DI*KC)/256, 256, 0, stream>>>(XZx, outF, b);
    // 4. x_proj -> PROJ f32
    k_sgemm_x<<<dim3(2, 32), 256, 0, stream>>>(XCbf, x_proj_w, PROJ, S_, 96, DI);
    // 5. small RMSNorms
    k_norms<<<S_, 64, 0, stream>>>(PROJ, dt_ln_w, b_ln_w, c_ln_w, NDT, BC);
    // 6. dt projection + softplus -> DT f32
    k_dtproj<<<dim3(DI/256, S_/16), 256, 0, stream>>>(NDT, dt_proj_w, dt_proj_b, DT);
    // 7. chunked parallel scan
    k_scan1<<<(DI*DSTATE*NC)/256, 256, 0, stream>>>(DT, XCbf, BC, A_log, SC_A, SC_H);
    k_scan2<<<(DI*DSTATE)/256, 256, 0, stream>>>(SC_A, SC_H, SC_S, outF, b);
    k_scan3<<<(DI*DSTATE*NC)/256, 256, 0, stream>>>(DT, XCbf, BC, A_log, D_skip, SC_S, ZY);
    // 8. out_proj MFMA + residual -> out_b (f32 HID)
    k_mfma<1><<<dim3(8, 16), 256, 0, stream>>>(ZY, WT_out, nullptr, hs_b,
        nullptr, nullptr, out_b, S_, DM, DI);
    // 9. pre-MoE RMSNorm -> bf16
    k_rms<<<S_, 256, 0, stream>>>(out_b, pre_moe_ln, HN_bf);
    // 10. gate/up dual MFMA -> FF bf16 (aliases XZx, dead by now)
    k_mfma<2><<<dim3(32, 16), 256, 0, stream>>>(HN_bf, WT_gate, WT_up, nullptr,
        nullptr, FFbf, nullptr, S_, DFF, DM);
    // 11. down MFMA + residual(out_b) -> out_b final
    k_mfma<1><<<dim3(8, 16), 256, 0, stream>>>(FFbf, WT_down, nullptr, out_b,
        nullptr, nullptr, out_b, S_, DM, DFF);
  }
}

// Round 5
// 911.379 us; speedup vs baseline: 5.6558x; 1.7190x over previous
//
#include <hip/hip_runtime.h>
#include <hip/hip_bf16.h>

#define B_ 2
#define S_ 2048
#define DM 1024
#define DI 2048
#define DSTATE 16
#define DTR 64
#define KC 4
#define DFF 4096
#define EPSF 1e-6f
#define NC 16
#define LCH (S_/NC)
#define KS 16
#define KCH (DI/KS)

#define CONV_OFF (B_*S_*DM)
#define SSM_OFF  (CONV_OFF + B_*DI*KC)

typedef __attribute__((ext_vector_type(8))) short short8;
typedef __attribute__((ext_vector_type(4))) float f32x4;

__device__ __forceinline__ float siluf(float x){ return x / (1.f + __expf(-x)); }
__device__ __forceinline__ float softplusf(float x){
  return (x > 0.f) ? (x + log1pf(__expf(-x))) : log1pf(__expf(x));
}
__device__ __forceinline__ float us2f(ushort u){
  union { float f; unsigned u32; } v; v.u32 = ((unsigned)u) << 16; return v.f;
}
__device__ __forceinline__ ushort f2us(float f){
  __hip_bfloat16 h = __float2bfloat16(f);
  return *reinterpret_cast<ushort*>(&h);
}
__device__ __forceinline__ void gld16(const ushort* g, ushort* l) {
  __builtin_amdgcn_global_load_lds(
      (const __attribute__((address_space(1))) void*)g,
      (__attribute__((address_space(3))) void*)l, 16, 0, 0);
}

// ---------------- weight convert+transpose: W f32 [K][N] -> WT bf16 [N][K] --------
__global__ __launch_bounds__(256) void k_wt(const float* __restrict__ W,
    ushort* __restrict__ WT, int K, int N) {
  __shared__ float t[32][33];
  int n0 = blockIdx.x * 32, k0 = blockIdx.y * 32;
  int tx = threadIdx.x & 31, ty = threadIdx.x >> 5;   // 32 x 8
  #pragma unroll
  for (int i = 0; i < 4; ++i) t[ty + i*8][tx] = W[(size_t)(k0 + ty + i*8)*N + n0 + tx];
  __syncthreads();
  #pragma unroll
  for (int i = 0; i < 4; ++i)
    WT[(size_t)(n0 + ty + i*8)*K + k0 + tx] = f2us(t[tx][ty + i*8]);
}

// ---------------- RMSNorm (D=1024), f32 in -> bf16 out ---------------------------
__global__ __launch_bounds__(256) void k_rms(const float* __restrict__ in,
    const float* __restrict__ w, ushort* __restrict__ out) {
  int t = blockIdx.x, tid = threadIdx.x;
  const int base = t * DM;
  float v[4]; float ss = 0.f;
  #pragma unroll
  for (int i = 0; i < 4; ++i) {
    float x = in[base + tid + i*256];
    v[i] = x; ss += x * x;
  }
  #pragma unroll
  for (int m = 1; m < 64; m <<= 1) ss += __shfl_xor(ss, m, 64);
  __shared__ float sred[4];
  if ((tid & 63) == 0) sred[tid >> 6] = ss;
  __syncthreads();
  float tot = sred[0] + sred[1] + sred[2] + sred[3];
  float r = rsqrtf(tot * (1.f / DM) + EPSF);
  #pragma unroll
  for (int i = 0; i < 4; ++i)
    out[base + tid + i*256] = f2us(v[i] * r * w[tid + i*256]);
}

// ---------------- MFMA GEMM, m97-style: global_load_lds + st_16x32 swizzle -------
// A[M][K] bf16 * WT[N][K] bf16 -> 128 x BN tile, BK=32, 4 waves.
// MODE 0 (in_proj): n<DI -> XZx f32 ; n>=DI -> ZY bf16
// MODE 1 (add):     outF = acc + Res(f32)
// MODE 2 (gate/up): outU = bf16(silu(acc)*acc2)
template<int MODE, int BN>
__global__ __launch_bounds__(256) void k_mfma(
    const ushort* __restrict__ Ag, const ushort* __restrict__ B1,
    const ushort* __restrict__ B2, const float* __restrict__ Res,
    float* __restrict__ XZx, ushort* __restrict__ outU,
    float* __restrict__ outF, int M, int N, int K)
{
  __shared__ __attribute__((aligned(16))) ushort As[128*32];
  __shared__ __attribute__((aligned(16))) ushort Bs[BN*32];
  __shared__ __attribute__((aligned(16))) ushort Bs2[(MODE==2)?BN*32:8];
  constexpr int NFM = (BN==128)?4:2;
  constexpr int BCH = BN*32*2/1024;           // 8 or 4 1KB-chunks
  int tid = threadIdx.x;
  int gn0 = blockIdx.x * BN, gm0 = blockIdx.y * 128;
  int wid = tid >> 6, lane = tid & 63;
  int mo = (BN==128) ? (wid>>1)*64 : wid*32;
  int no = (BN==128) ? (wid&1)*64 : 0;
  int lr = lane & 15, lk = lane >> 4;
  // staging address: 1KB chunk = 16 rows x 32 cols; lane l -> row l/4,
  // col pre-swizzled (st_16x32: XOR 16-elem block with row bit3 == lane bit5)
  int srow = lane >> 2;
  int scol = ((lane & 3) * 8) ^ ((lane & 32) ? 16 : 0);

  f32x4 acc[NFM][4];
  f32x4 acc2[(MODE==2)?NFM:1][(MODE==2)?4:1];
  #pragma unroll
  for (int i = 0; i < NFM; ++i)
    #pragma unroll
    for (int j = 0; j < 4; ++j) {
      acc[i][j] = (f32x4){0.f,0.f,0.f,0.f};
      if (MODE == 2) acc2[i][j] = (f32x4){0.f,0.f,0.f,0.f};
    }

  for (int k0 = 0; k0 < K; k0 += 32) {
    for (int ch = wid; ch < 8; ch += 4)
      gld16(Ag + (size_t)(gm0 + ch*16 + srow)*K + k0 + scol, &As[ch*512]);
    for (int ch = wid; ch < BCH; ch += 4)
      gld16(B1 + (size_t)(gn0 + ch*16 + srow)*K + k0 + scol, &Bs[ch*512]);
    if (MODE == 2)
      for (int ch = wid; ch < BCH; ch += 4)
        gld16(B2 + (size_t)(gn0 + ch*16 + srow)*K + k0 + scol, &Bs2[ch*512]);
    __syncthreads();
    // swizzled fragment reads: col = lk*8 XOR (row&8 ? 16 : 0)
    int rcsw = (lr & 8) ? 16 : 0;
    short8 af[NFM], bfr[4], bfr2[(MODE==2)?4:1];
    #pragma unroll
    for (int mi = 0; mi < NFM; ++mi)
      af[mi] = *(const short8*)&As[(mo + mi*16 + lr)*32 + (lk*8 ^ rcsw)];
    #pragma unroll
    for (int ni = 0; ni < 4; ++ni) {
      bfr[ni] = *(const short8*)&Bs[(no + ni*16 + lr)*32 + (lk*8 ^ rcsw)];
      if (MODE == 2) bfr2[ni] = *(const short8*)&Bs2[(no + ni*16 + lr)*32 + (lk*8 ^ rcsw)];
    }
    #pragma unroll
    for (int mi = 0; mi < NFM; ++mi)
      #pragma unroll
      for (int ni = 0; ni < 4; ++ni) {
        acc[mi][ni] = __builtin_amdgcn_mfma_f32_16x16x32_bf16(af[mi], bfr[ni], acc[mi][ni], 0, 0, 0);
        if (MODE == 2)
          acc2[mi][ni] = __builtin_amdgcn_mfma_f32_16x16x32_bf16(af[mi], bfr2[ni], acc2[mi][ni], 0, 0, 0);
      }
    __syncthreads();
  }

  #pragma unroll
  for (int mi = 0; mi < NFM; ++mi)
    #pragma unroll
    for (int ni = 0; ni < 4; ++ni)
      #pragma unroll
      for (int r = 0; r < 4; ++r) {
        int gr = gm0 + mo + mi*16 + lk*4 + r;
        int gc = gn0 + no + ni*16 + lr;
        float v = acc[mi][ni][r];
        size_t idx = (size_t)gr*N + gc;
        if (MODE == 0) {
          if (gc < DI) XZx[(size_t)gr*DI + gc] = v;
          else         outU[(size_t)gr*DI + gc - DI] = f2us(v);
        } else if (MODE == 1) {
          outF[idx] = v + Res[idx];
        } else {
          outU[idx] = f2us(siluf(v) * acc2[mi][ni][r]);
        }
      }
}

// ---------------- x_proj split-K: A bf16 [S][DI] * B f32 [DI][96] -> partials -----
__global__ __launch_bounds__(256) void k_xproj(const ushort* __restrict__ A,
    const float* __restrict__ Bw, float* __restrict__ PP) {
  __shared__ float As[16][65];
  __shared__ float Bsh[16][96];
  int tid = threadIdx.x;
  int ks = blockIdx.x, mt = blockIdx.y;
  int m0 = mt*64, k0 = ks*KCH;
  int r0 = (tid >> 4) * 4, c0 = (tid & 15) * 6;
  float acc[4][6] = {};
  for (int kk0 = 0; kk0 < KCH; kk0 += 16) {
    #pragma unroll
    for (int i = 0; i < 4; ++i) {
      int e = tid + i*256;
      As[e & 15][e >> 4] = us2f(A[(size_t)(m0 + (e >> 4))*DI + k0 + kk0 + (e & 15)]);
    }
    #pragma unroll
    for (int i = 0; i < 6; ++i) {
      int e = tid + i*256;     // < 1536
      int kk = e / 96, c = e - kk*96;
      Bsh[kk][c] = Bw[(size_t)(k0 + kk0 + kk)*96 + c];
    }
    __syncthreads();
    #pragma unroll
    for (int kk = 0; kk < 16; ++kk) {
      float a[4], bv[6];
      #pragma unroll
      for (int i = 0; i < 4; ++i) a[i] = As[kk][r0 + i];
      #pragma unroll
      for (int j = 0; j < 6; ++j) bv[j] = Bsh[kk][c0 + j];
      #pragma unroll
      for (int i = 0; i < 4; ++i)
        #pragma unroll
        for (int j = 0; j < 6; ++j) acc[i][j] += a[i] * bv[j];
    }
    __syncthreads();
  }
  float* dst = PP + (size_t)ks*S_*96;
  #pragma unroll
  for (int i = 0; i < 4; ++i)
    #pragma unroll
    for (int j = 0; j < 6; ++j)
      dst[(size_t)(m0 + r0 + i)*96 + c0 + j] = acc[i][j];
}

__global__ __launch_bounds__(256) void k_xred(const float* __restrict__ PP,
    float* __restrict__ PROJ) {
  int i = blockIdx.x*256 + threadIdx.x;   // < S_*96
  float s = 0.f;
  #pragma unroll
  for (int ks = 0; ks < KS; ++ks) s += PP[(size_t)ks*S_*96 + i];
  PROJ[i] = s;
}

// ---------------- depthwise causal conv + bias + silu: XZx f32 -> XC bf16 --------
__global__ __launch_bounds__(256) void k_conv(const float* __restrict__ XZx,
    const float* __restrict__ cw, const float* __restrict__ cb,
    ushort* __restrict__ XC) {
  int i = blockIdx.x * 256 + threadIdx.x;        // s*DI + d
  int d = i & (DI - 1);
  int s = i >> 11;
  float acc = cb[d];
  #pragma unroll
  for (int k = 0; k < KC; ++k) {
    int s2 = s - (KC - 1) + k;
    if (s2 >= 0) acc += XZx[s2*DI + d] * cw[d*KC + k];
  }
  XC[i] = f2us(siluf(acc));
}

// ---------------- conv_state: XZx[S-4+k, d] -> out (b,d,k) f32 -------------------
__global__ __launch_bounds__(256) void k_convstate(const float* __restrict__ XZx,
    float* __restrict__ outF, int b) {
  int i = blockIdx.x * 256 + threadIdx.x;        // d*KC + k, < 8192
  int k = i & 3;
  int d = i >> 2;
  outF[CONV_OFF + b*DI*KC + i] = XZx[(S_ - KC + k)*DI + d];
}

// ---------------- per-token small RMSNorms (dt 64, B 16, C 16) -------------------
__global__ __launch_bounds__(64) void k_norms(const float* __restrict__ PROJ,
    const float* __restrict__ dtw, const float* __restrict__ bw,
    const float* __restrict__ cw, float* __restrict__ NDT,
    float* __restrict__ BC) {
  int t = blockIdx.x, lane = threadIdx.x;
  float v = PROJ[t*96 + lane];
  float ss = v * v;
  #pragma unroll
  for (int m = 1; m < 64; m <<= 1) ss += __shfl_xor(ss, m, 64);
  float r = rsqrtf(ss * (1.f / DTR) + EPSF);
  NDT[t*DTR + lane] = v * r * dtw[lane];
  if (lane < 32) {
    float u = PROJ[t*96 + 64 + lane];
    float s2 = u * u;
    #pragma unroll
    for (int m = 1; m < 16; m <<= 1) s2 += __shfl_xor(s2, m, 16);
    float r2 = rsqrtf(s2 * (1.f / DSTATE) + EPSF);
    float wv = (lane < 16) ? bw[lane] : cw[lane - 16];
    BC[t*32 + lane] = u * r2 * wv;
  }
}

// ---------------- dt projection: (S x 64) @ (64 x DI) + bias, softplus -> f32 ----
__global__ __launch_bounds__(256) void k_dtproj(const float* __restrict__ NDT,
    const float* __restrict__ W, const float* __restrict__ bias,
    float* __restrict__ DT) {
  __shared__ float nd[16][64];
  int tid = threadIdx.x;
  int d = blockIdx.x * 256 + tid;
  int t0 = blockIdx.y * 16;
  #pragma unroll
  for (int i = 0; i < 4; ++i) {
    int idx = tid + i*256;
    nd[idx >> 6][idx & 63] = NDT[(t0 + (idx >> 6))*DTR + (idx & 63)];
  }
  __syncthreads();
  float acc[16] = {};
  for (int k = 0; k < 64; ++k) {
    float wv = W[k*DI + d];
    #pragma unroll
    for (int tk = 0; tk < 16; ++tk) acc[tk] += nd[tk][k] * wv;
  }
  float bv = bias[d];
  #pragma unroll
  for (int tk = 0; tk < 16; ++tk)
    DT[(t0 + tk)*DI + d] = softplusf(acc[tk] + bv);
}

// ---------------- scan phase 1: per-chunk (prod dA, local h) ---------------------
__global__ __launch_bounds__(256) void k_scan1(const float* __restrict__ DT,
    const ushort* __restrict__ XC, const float* __restrict__ BC,
    const float* __restrict__ A_log, float* __restrict__ scA,
    float* __restrict__ scH) {
  int g = blockIdx.x * 256 + threadIdx.x;   // c*32768 + d*16 + n
  int n = g & 15, d = (g >> 4) & (DI - 1), c = g >> 15;
  float A = -__expf(A_log[d*DSTATE + n]);
  float h = 0.f, ap = 1.f;
  int t0 = c * LCH;
  for (int i = 0; i < LCH; ++i) {
    int t = t0 + i;
    float dtv = DT[t*DI + d];
    float xv  = us2f(XC[t*DI + d]);
    float Bn  = BC[t*32 + n];
    float dA = __expf(dtv * A);
    h = h * dA + dtv * xv * Bn;
    ap *= dA;
  }
  int idx = (d*DSTATE + n)*NC + c;
  scA[idx] = ap; scH[idx] = h;
}

// ---------------- scan phase 2: combine chunks; emit h_start + ssm_state ---------
__global__ __launch_bounds__(256) void k_scan2(const float* __restrict__ scA,
    const float* __restrict__ scH, float* __restrict__ scS,
    float* __restrict__ outF, int b) {
  int g = blockIdx.x * 256 + threadIdx.x;   // d*16 + n, < 32768
  int base = g * NC;
  float h = 0.f;
  #pragma unroll
  for (int c = 0; c < NC; ++c) {
    scS[base + c] = h;
    h = scA[base + c] * h + scH[base + c];
  }
  outF[SSM_OFF + b*DI*DSTATE + g] = h;
}

// ---------------- scan phase 3: replay with h_start; fused y*silu(z) -> ZY bf16 --
__global__ __launch_bounds__(256) void k_scan3(const float* __restrict__ DT,
    const ushort* __restrict__ XC, const float* __restrict__ BC,
    const float* __restrict__ A_log, const float* __restrict__ Dskip,
    const float* __restrict__ scS, ushort* ZY) {
  int g = blockIdx.x * 256 + threadIdx.x;
  int n = g & 15, d = (g >> 4) & (DI - 1), c = g >> 15;
  float A = -__expf(A_log[d*DSTATE + n]);
  float Dd = Dskip[d];
  float h = scS[(d*DSTATE + n)*NC + c];
  int t0 = c * LCH;
  for (int i = 0; i < LCH; ++i) {
    int t = t0 + i;
    float dtv = DT[t*DI + d];
    float xv  = us2f(XC[t*DI + d]);
    float Bn  = BC[t*32 + n];
    float Cn  = BC[t*32 + 16 + n];
    float dA = __expf(dtv * A);
    h = h * dA + dtv * xv * Bn;
    float p = h * Cn;
    p += __shfl_xor(p, 1, 16);
    p += __shfl_xor(p, 2, 16);
    p += __shfl_xor(p, 4, 16);
    p += __shfl_xor(p, 8, 16);
    if (n == 0) {
      float zv = us2f(ZY[t*DI + d]);
      ZY[t*DI + d] = f2us((p + Dd * xv) * siluf(zv));
    }
  }
}

extern "C" void kernel_launch(void* const* d_in, const int* in_sizes, int n_in,
                              void* d_out, int out_size, void* d_ws, size_t ws_size,
                              hipStream_t stream) {
  const float* hs         = (const float*)d_in[0];
  const float* in_proj_w  = (const float*)d_in[1];
  const float* conv_w     = (const float*)d_in[2];
  const float* conv_b     = (const float*)d_in[3];
  const float* x_proj_w   = (const float*)d_in[4];
  const float* dt_proj_w  = (const float*)d_in[5];
  const float* dt_proj_b  = (const float*)d_in[6];
  const float* dt_ln_w    = (const float*)d_in[7];
  const float* b_ln_w     = (const float*)d_in[8];
  const float* c_ln_w     = (const float*)d_in[9];
  const float* A_log      = (const float*)d_in[10];
  const float* D_skip     = (const float*)d_in[11];
  const float* out_proj_w = (const float*)d_in[12];
  const float* input_ln_w = (const float*)d_in[13];
  const float* pre_moe_ln = (const float*)d_in[14];
  const float* gate_w     = (const float*)d_in[15];
  const float* up_w       = (const float*)d_in[16];
  const float* down_w     = (const float*)d_in[17];
  float* outF = (float*)d_out;

  // ---- workspace (~89.5 MB with aliasing) ----
  char* p = (char*)d_ws;
  auto alloc = [&](size_t bytes) { void* r = (void*)p; p += (bytes + 255) & ~(size_t)255; return r; };
  ushort* WT_in   = (ushort*)alloc((size_t)4096*1024*2);
  ushort* WT_out  = (ushort*)alloc((size_t)1024*2048*2);
  ushort* WT_gate = (ushort*)alloc((size_t)4096*1024*2);
  ushort* WT_up   = (ushort*)alloc((size_t)4096*1024*2);
  ushort* WT_down = (ushort*)alloc((size_t)1024*4096*2);
  ushort* HN_bf   = (ushort*)alloc((size_t)S_*DM*2);
  ushort* XCbf    = (ushort*)alloc((size_t)S_*DI*2);
  ushort* ZY      = (ushort*)alloc((size_t)S_*DI*2);     // z, later y*silu(z)
  float*  XZx     = (float*) alloc((size_t)S_*DI*4);     // x pre-conv (steps 2-3b)
  float*  DT      = (float*) alloc((size_t)S_*DI*4);     // dt (step 6+)
  float*  PROJ    = (float*) alloc((size_t)S_*96*4);
  float*  NDT     = (float*) alloc((size_t)S_*DTR*4);
  float*  BC      = (float*) alloc((size_t)S_*32*4);
  // aliases (lifetime-disjoint):
  ushort* FFbf  = (ushort*)XZx;               // FFN act (steps 10-11); XZx dead
  float*  PROJP = DT;                         // x_proj partials (4-4b); DT written at 6
  float*  SC_A  = XZx;                        // scan scratch (7); XZx dead
  float*  SC_H  = SC_A + (size_t)DI*DSTATE*NC;
  float*  SC_S  = SC_H + (size_t)DI*DSTATE*NC;

  // ---- one-time weight convert+transpose to bf16 [N][K] ----
  k_wt<<<dim3(4096/32, 1024/32), 256, 0, stream>>>(in_proj_w,  WT_in,   1024, 4096);
  k_wt<<<dim3(1024/32, 2048/32), 256, 0, stream>>>(out_proj_w, WT_out,  2048, 1024);
  k_wt<<<dim3(4096/32, 1024/32), 256, 0, stream>>>(gate_w,     WT_gate, 1024, 4096);
  k_wt<<<dim3(4096/32, 1024/32), 256, 0, stream>>>(up_w,       WT_up,   1024, 4096);
  k_wt<<<dim3(1024/32, 4096/32), 256, 0, stream>>>(down_w,     WT_down, 4096, 1024);

  for (int b = 0; b < B_; ++b) {
    const float* hs_b  = hs   + (size_t)b*S_*DM;
    float*       out_b = outF + (size_t)b*S_*DM;   // HID (f32), then final out

    // 1. input RMSNorm -> bf16
    k_rms<<<S_, 256, 0, stream>>>(hs_b, input_ln_w, HN_bf);
    // 2. in_proj MFMA: x-half -> XZx f32, z-half -> ZY bf16
    k_mfma<0,128><<<dim3(32, 16), 256, 0, stream>>>(HN_bf, WT_in, nullptr, nullptr,
        XZx, ZY, nullptr, S_, 2*DI, DM);
    // 3. conv + silu -> XC bf16
    k_conv<<<(S_*DI)/256, 256, 0, stream>>>(XZx, conv_w, conv_b, XCbf);
    // 3b. conv_state (f32 path)
    k_convstate<<<(DI*KC)/256, 256, 0, stream>>>(XZx, outF, b);
    // 4. x_proj split-K -> partials; 4b. reduce -> PROJ
    k_xproj<<<dim3(KS, S_/64), 256, 0, stream>>>(XCbf, x_proj_w, PROJP);
    k_xred<<<(S_*96)/256, 256, 0, stream>>>(PROJP, PROJ);
    // 5. small RMSNorms
    k_norms<<<S_, 64, 0, stream>>>(PROJ, dt_ln_w, b_ln_w, c_ln_w, NDT, BC);
    // 6. dt projection + softplus -> DT f32
    k_dtproj<<<dim3(DI/256, S_/16), 256, 0, stream>>>(NDT, dt_proj_w, dt_proj_b, DT);
    // 7. chunked parallel scan (NC=16)
    k_scan1<<<(DI*DSTATE*NC)/256, 256, 0, stream>>>(DT, XCbf, BC, A_log, SC_A, SC_H);
    k_scan2<<<(DI*DSTATE)/256, 256, 0, stream>>>(SC_A, SC_H, SC_S, outF, b);
    k_scan3<<<(DI*DSTATE*NC)/256, 256, 0, stream>>>(DT, XCbf, BC, A_log, D_skip, SC_S, ZY);
    // 8. out_proj MFMA + residual -> out_b (f32 HID)
    k_mfma<1,64><<<dim3(16, 16), 256, 0, stream>>>(ZY, WT_out, nullptr, hs_b,
        nullptr, nullptr, out_b, S_, DM, DI);
    // 9. pre-MoE RMSNorm -> bf16
    k_rms<<<S_, 256, 0, stream>>>(out_b, pre_moe_ln, HN_bf);
    // 10. gate/up dual MFMA -> FFbf
    k_mfma<2,128><<<dim3(32, 16), 256, 0, stream>>>(HN_bf, WT_gate, WT_up, nullptr,
        nullptr, FFbf, nullptr, S_, DFF, DM);
    // 11. down MFMA + residual(out_b) -> out_b final
    k_mfma<1,64><<<dim3(16, 16), 256, 0, stream>>>(FFbf, WT_down, nullptr, out_b,
        nullptr, nullptr, out_b, S_, DM, DFF);
  }
}

// Round 6
// 807.458 us; speedup vs baseline: 6.3837x; 1.1287x over previous
//
#include <hip/hip_runtime.h>
#include <hip/hip_bf16.h>

#define B_ 2
#define S_ 2048
#define DM 1024
#define DI 2048
#define DSTATE 16
#define DTR 64
#define KC 4
#define DFF 4096
#define EPSF 1e-6f
#define NC 64
#define LCH (S_/NC)
#define KS 16
#define KCH (DI/KS)

#define CONV_OFF (B_*S_*DM)
#define SSM_OFF  (CONV_OFF + B_*DI*KC)

typedef __attribute__((ext_vector_type(8))) short short8;
typedef __attribute__((ext_vector_type(4))) float f32x4;

__device__ __forceinline__ float siluf(float x){ return x / (1.f + __expf(-x)); }
__device__ __forceinline__ float softplusf(float x){
  return (x > 0.f) ? (x + log1pf(__expf(-x))) : log1pf(__expf(x));
}
__device__ __forceinline__ float us2f(ushort u){
  union { float f; unsigned u32; } v; v.u32 = ((unsigned)u) << 16; return v.f;
}
__device__ __forceinline__ ushort f2us(float f){
  __hip_bfloat16 h = __float2bfloat16(f);
  return *reinterpret_cast<ushort*>(&h);
}
__device__ __forceinline__ void gld16(const ushort* g, ushort* l) {
  __builtin_amdgcn_global_load_lds(
      (const __attribute__((address_space(1))) void*)g,
      (__attribute__((address_space(3))) void*)l, 16, 0, 0);
}

// ---------------- weight convert+transpose: W f32 [K][N] -> WT bf16 [N][K] --------
__global__ __launch_bounds__(256) void k_wt(const float* __restrict__ W,
    ushort* __restrict__ WT, int K, int N) {
  __shared__ float t[32][33];
  int n0 = blockIdx.x * 32, k0 = blockIdx.y * 32;
  int tx = threadIdx.x & 31, ty = threadIdx.x >> 5;   // 32 x 8
  #pragma unroll
  for (int i = 0; i < 4; ++i) t[ty + i*8][tx] = W[(size_t)(k0 + ty + i*8)*N + n0 + tx];
  __syncthreads();
  #pragma unroll
  for (int i = 0; i < 4; ++i)
    WT[(size_t)(n0 + ty + i*8)*K + k0 + tx] = f2us(t[tx][ty + i*8]);
}

// ---------------- RMSNorm (D=1024), f32 in -> bf16 out ---------------------------
__global__ __launch_bounds__(256) void k_rms(const float* __restrict__ in,
    const float* __restrict__ w, ushort* __restrict__ out) {
  int t = blockIdx.x, tid = threadIdx.x;
  const int base = t * DM;
  float v[4]; float ss = 0.f;
  #pragma unroll
  for (int i = 0; i < 4; ++i) {
    float x = in[base + tid + i*256];
    v[i] = x; ss += x * x;
  }
  #pragma unroll
  for (int m = 1; m < 64; m <<= 1) ss += __shfl_xor(ss, m, 64);
  __shared__ float sred[4];
  if ((tid & 63) == 0) sred[tid >> 6] = ss;
  __syncthreads();
  float tot = sred[0] + sred[1] + sred[2] + sred[3];
  float r = rsqrtf(tot * (1.f / DM) + EPSF);
  #pragma unroll
  for (int i = 0; i < 4; ++i)
    out[base + tid + i*256] = f2us(v[i] * r * w[tid + i*256]);
}

// ---------------- MFMA GEMM, m97-style: global_load_lds + st_16x32 swizzle -------
template<int MODE, int BN>
__global__ __launch_bounds__(256) void k_mfma(
    const ushort* __restrict__ Ag, const ushort* __restrict__ B1,
    const ushort* __restrict__ B2, const float* __restrict__ Res,
    float* __restrict__ XZx, ushort* __restrict__ outU,
    float* __restrict__ outF, int M, int N, int K)
{
  __shared__ __attribute__((aligned(16))) ushort As[128*32];
  __shared__ __attribute__((aligned(16))) ushort Bs[BN*32];
  __shared__ __attribute__((aligned(16))) ushort Bs2[(MODE==2)?BN*32:8];
  constexpr int NFM = (BN==128)?4:2;
  constexpr int BCH = BN*32*2/1024;
  int tid = threadIdx.x;
  int gn0 = blockIdx.x * BN, gm0 = blockIdx.y * 128;
  int wid = tid >> 6, lane = tid & 63;
  int mo = (BN==128) ? (wid>>1)*64 : wid*32;
  int no = (BN==128) ? (wid&1)*64 : 0;
  int lr = lane & 15, lk = lane >> 4;
  int srow = lane >> 2;
  int scol = ((lane & 3) * 8) ^ ((lane & 32) ? 16 : 0);

  f32x4 acc[NFM][4];
  f32x4 acc2[(MODE==2)?NFM:1][(MODE==2)?4:1];
  #pragma unroll
  for (int i = 0; i < NFM; ++i)
    #pragma unroll
    for (int j = 0; j < 4; ++j) {
      acc[i][j] = (f32x4){0.f,0.f,0.f,0.f};
      if (MODE == 2) acc2[i][j] = (f32x4){0.f,0.f,0.f,0.f};
    }

  for (int k0 = 0; k0 < K; k0 += 32) {
    for (int ch = wid; ch < 8; ch += 4)
      gld16(Ag + (size_t)(gm0 + ch*16 + srow)*K + k0 + scol, &As[ch*512]);
    for (int ch = wid; ch < BCH; ch += 4)
      gld16(B1 + (size_t)(gn0 + ch*16 + srow)*K + k0 + scol, &Bs[ch*512]);
    if (MODE == 2)
      for (int ch = wid; ch < BCH; ch += 4)
        gld16(B2 + (size_t)(gn0 + ch*16 + srow)*K + k0 + scol, &Bs2[ch*512]);
    __syncthreads();
    int rcsw = (lr & 8) ? 16 : 0;
    short8 af[NFM], bfr[4], bfr2[(MODE==2)?4:1];
    #pragma unroll
    for (int mi = 0; mi < NFM; ++mi)
      af[mi] = *(const short8*)&As[(mo + mi*16 + lr)*32 + (lk*8 ^ rcsw)];
    #pragma unroll
    for (int ni = 0; ni < 4; ++ni) {
      bfr[ni] = *(const short8*)&Bs[(no + ni*16 + lr)*32 + (lk*8 ^ rcsw)];
      if (MODE == 2) bfr2[ni] = *(const short8*)&Bs2[(no + ni*16 + lr)*32 + (lk*8 ^ rcsw)];
    }
    #pragma unroll
    for (int mi = 0; mi < NFM; ++mi)
      #pragma unroll
      for (int ni = 0; ni < 4; ++ni) {
        acc[mi][ni] = __builtin_amdgcn_mfma_f32_16x16x32_bf16(af[mi], bfr[ni], acc[mi][ni], 0, 0, 0);
        if (MODE == 2)
          acc2[mi][ni] = __builtin_amdgcn_mfma_f32_16x16x32_bf16(af[mi], bfr2[ni], acc2[mi][ni], 0, 0, 0);
      }
    __syncthreads();
  }

  #pragma unroll
  for (int mi = 0; mi < NFM; ++mi)
    #pragma unroll
    for (int ni = 0; ni < 4; ++ni)
      #pragma unroll
      for (int r = 0; r < 4; ++r) {
        int gr = gm0 + mo + mi*16 + lk*4 + r;
        int gc = gn0 + no + ni*16 + lr;
        float v = acc[mi][ni][r];
        size_t idx = (size_t)gr*N + gc;
        if (MODE == 0) {
          if (gc < DI) XZx[(size_t)gr*DI + gc] = v;
          else         outU[(size_t)gr*DI + gc - DI] = f2us(v);
        } else if (MODE == 1) {
          outF[idx] = v + Res[idx];
        } else {
          outU[idx] = f2us(siluf(v) * acc2[mi][ni][r]);
        }
      }
}

// ---------------- x_proj split-K: A bf16 [S][DI] * B f32 [DI][96] -> partials -----
__global__ __launch_bounds__(256) void k_xproj(const ushort* __restrict__ A,
    const float* __restrict__ Bw, float* __restrict__ PP) {
  __shared__ float As[16][65];
  __shared__ float Bsh[16][96];
  int tid = threadIdx.x;
  int ks = blockIdx.x, mt = blockIdx.y;
  int m0 = mt*64, k0 = ks*KCH;
  int r0 = (tid >> 4) * 4, c0 = (tid & 15) * 6;
  float acc[4][6] = {};
  for (int kk0 = 0; kk0 < KCH; kk0 += 16) {
    #pragma unroll
    for (int i = 0; i < 4; ++i) {
      int e = tid + i*256;
      As[e & 15][e >> 4] = us2f(A[(size_t)(m0 + (e >> 4))*DI + k0 + kk0 + (e & 15)]);
    }
    #pragma unroll
    for (int i = 0; i < 6; ++i) {
      int e = tid + i*256;
      int kk = e / 96, c = e - kk*96;
      Bsh[kk][c] = Bw[(size_t)(k0 + kk0 + kk)*96 + c];
    }
    __syncthreads();
    #pragma unroll
    for (int kk = 0; kk < 16; ++kk) {
      float a[4], bv[6];
      #pragma unroll
      for (int i = 0; i < 4; ++i) a[i] = As[kk][r0 + i];
      #pragma unroll
      for (int j = 0; j < 6; ++j) bv[j] = Bsh[kk][c0 + j];
      #pragma unroll
      for (int i = 0; i < 4; ++i)
        #pragma unroll
        for (int j = 0; j < 6; ++j) acc[i][j] += a[i] * bv[j];
    }
    __syncthreads();
  }
  float* dst = PP + (size_t)ks*S_*96;
  #pragma unroll
  for (int i = 0; i < 4; ++i)
    #pragma unroll
    for (int j = 0; j < 6; ++j)
      dst[(size_t)(m0 + r0 + i)*96 + c0 + j] = acc[i][j];
}

__global__ __launch_bounds__(256) void k_xred(const float* __restrict__ PP,
    float* __restrict__ PROJ) {
  int i = blockIdx.x*256 + threadIdx.x;
  float s = 0.f;
  #pragma unroll
  for (int ks = 0; ks < KS; ++ks) s += PP[(size_t)ks*S_*96 + i];
  PROJ[i] = s;
}

// ---------------- depthwise causal conv + bias + silu: XZx f32 -> XC bf16 --------
__global__ __launch_bounds__(256) void k_conv(const float* __restrict__ XZx,
    const float* __restrict__ cw, const float* __restrict__ cb,
    ushort* __restrict__ XC) {
  int i = blockIdx.x * 256 + threadIdx.x;
  int d = i & (DI - 1);
  int s = i >> 11;
  float acc = cb[d];
  #pragma unroll
  for (int k = 0; k < KC; ++k) {
    int s2 = s - (KC - 1) + k;
    if (s2 >= 0) acc += XZx[s2*DI + d] * cw[d*KC + k];
  }
  XC[i] = f2us(siluf(acc));
}

// ---------------- conv_state: XZx[S-4+k, d] -> out (b,d,k) f32 -------------------
__global__ __launch_bounds__(256) void k_convstate(const float* __restrict__ XZx,
    float* __restrict__ outF, int b) {
  int i = blockIdx.x * 256 + threadIdx.x;
  int k = i & 3;
  int d = i >> 2;
  outF[CONV_OFF + b*DI*KC + i] = XZx[(S_ - KC + k)*DI + d];
}

// ---------------- per-token small RMSNorms (dt 64, B 16, C 16) -------------------
__global__ __launch_bounds__(64) void k_norms(const float* __restrict__ PROJ,
    const float* __restrict__ dtw, const float* __restrict__ bw,
    const float* __restrict__ cw, float* __restrict__ NDT,
    float* __restrict__ BC) {
  int t = blockIdx.x, lane = threadIdx.x;
  float v = PROJ[t*96 + lane];
  float ss = v * v;
  #pragma unroll
  for (int m = 1; m < 64; m <<= 1) ss += __shfl_xor(ss, m, 64);
  float r = rsqrtf(ss * (1.f / DTR) + EPSF);
  NDT[t*DTR + lane] = v * r * dtw[lane];
  if (lane < 32) {
    float u = PROJ[t*96 + 64 + lane];
    float s2 = u * u;
    #pragma unroll
    for (int m = 1; m < 16; m <<= 1) s2 += __shfl_xor(s2, m, 16);
    float r2 = rsqrtf(s2 * (1.f / DSTATE) + EPSF);
    float wv = (lane < 16) ? bw[lane] : cw[lane - 16];
    BC[t*32 + lane] = u * r2 * wv;
  }
}

// ---------------- dt projection: (S x 64) @ (64 x DI) + bias, softplus -> f32 ----
__global__ __launch_bounds__(256) void k_dtproj(const float* __restrict__ NDT,
    const float* __restrict__ W, const float* __restrict__ bias,
    float* __restrict__ DT) {
  __shared__ float nd[16][64];
  int tid = threadIdx.x;
  int d = blockIdx.x * 256 + tid;
  int t0 = blockIdx.y * 16;
  #pragma unroll
  for (int i = 0; i < 4; ++i) {
    int idx = tid + i*256;
    nd[idx >> 6][idx & 63] = NDT[(t0 + (idx >> 6))*DTR + (idx & 63)];
  }
  __syncthreads();
  float acc[16] = {};
  for (int k = 0; k < 64; ++k) {
    float wv = W[k*DI + d];
    #pragma unroll
    for (int tk = 0; tk < 16; ++tk) acc[tk] += nd[tk][k] * wv;
  }
  float bv = bias[d];
  #pragma unroll
  for (int tk = 0; tk < 16; ++tk)
    DT[(t0 + tk)*DI + d] = softplusf(acc[tk] + bv);
}

// ---------------- scan phase 1: thread per (d, chunk); h[16] in regs -------------
// carries layout: [c][d*16+n]  (coalesced stores here, coalesced loads in ph2/3)
__global__ __launch_bounds__(256) void k_scan1(const float* __restrict__ DT,
    const ushort* __restrict__ XC, const float* __restrict__ BC,
    const float* __restrict__ A_log, float* __restrict__ scA,
    float* __restrict__ scH) {
  int g = blockIdx.x * 256 + threadIdx.x;   // c*DI + d
  int d = g & (DI - 1), c = g >> 11;
  float A[16], h[16], ap[16];
  #pragma unroll
  for (int q = 0; q < 4; ++q) {
    f32x4 al = *(const f32x4*)(A_log + d*DSTATE + q*4);
    #pragma unroll
    for (int r = 0; r < 4; ++r) {
      A[q*4+r] = -__expf(al[r]);
      h[q*4+r] = 0.f; ap[q*4+r] = 1.f;
    }
  }
  int t0 = c * LCH;
  for (int i = 0; i < LCH; ++i) {
    int t = t0 + i;
    float dtv = DT[t*DI + d];
    float dtx = dtv * us2f(XC[t*DI + d]);
    const f32x4* bc = (const f32x4*)(BC + t*32);
    #pragma unroll
    for (int q = 0; q < 4; ++q) {
      f32x4 Bv = bc[q];
      #pragma unroll
      for (int r = 0; r < 4; ++r) {
        int n = q*4+r;
        float dA = __expf(dtv * A[n]);
        h[n] = h[n]*dA + dtx*Bv[r];
        ap[n] *= dA;
      }
    }
  }
  size_t base = (size_t)c*DI*DSTATE + d*DSTATE;
  #pragma unroll
  for (int q = 0; q < 4; ++q) {
    *(f32x4*)(scA + base + q*4) = (f32x4){ap[q*4],ap[q*4+1],ap[q*4+2],ap[q*4+3]};
    *(f32x4*)(scH + base + q*4) = (f32x4){h[q*4],h[q*4+1],h[q*4+2],h[q*4+3]};
  }
}

// ---------------- scan phase 2: combine; h_start written IN PLACE over scA -------
__global__ __launch_bounds__(256) void k_scan2(float* scAS,
    const float* __restrict__ scH, float* __restrict__ outF, int b) {
  int g = blockIdx.x * 256 + threadIdx.x;   // d*16+n, < 32768
  float h = 0.f;
  #pragma unroll 4
  for (int c = 0; c < NC; ++c) {
    size_t idx = (size_t)c*DI*DSTATE + g;
    float a = scAS[idx];
    float hh = scH[idx];
    scAS[idx] = h;            // h_start for chunk c
    h = a*h + hh;
  }
  outF[SSM_OFF + b*DI*DSTATE + g] = h;
}

// ---------------- scan phase 3: replay with h_start; in-reg C-dot; y*silu(z) -----
__global__ __launch_bounds__(256) void k_scan3(const float* __restrict__ DT,
    const ushort* __restrict__ XC, const float* __restrict__ BC,
    const float* __restrict__ A_log, const float* __restrict__ Dskip,
    const float* __restrict__ scS, ushort* ZY) {
  int g = blockIdx.x * 256 + threadIdx.x;   // c*DI + d
  int d = g & (DI - 1), c = g >> 11;
  float A[16], h[16];
  size_t base = (size_t)c*DI*DSTATE + d*DSTATE;
  #pragma unroll
  for (int q = 0; q < 4; ++q) {
    f32x4 al = *(const f32x4*)(A_log + d*DSTATE + q*4);
    f32x4 h0 = *(const f32x4*)(scS + base + q*4);
    #pragma unroll
    for (int r = 0; r < 4; ++r) {
      A[q*4+r] = -__expf(al[r]);
      h[q*4+r] = h0[r];
    }
  }
  float Dd = Dskip[d];
  int t0 = c * LCH;
  for (int i = 0; i < LCH; ++i) {
    int t = t0 + i;
    float dtv = DT[t*DI + d];
    float xv  = us2f(XC[t*DI + d]);
    float dtx = dtv * xv;
    const f32x4* bc = (const f32x4*)(BC + t*32);
    float p = 0.f;
    #pragma unroll
    for (int q = 0; q < 4; ++q) {
      f32x4 Bv = bc[q];
      f32x4 Cv = bc[4+q];
      #pragma unroll
      for (int r = 0; r < 4; ++r) {
        int n = q*4+r;
        float dA = __expf(dtv * A[n]);
        h[n] = h[n]*dA + dtx*Bv[r];
        p += h[n]*Cv[r];
      }
    }
    float zv = us2f(ZY[t*DI + d]);
    ZY[t*DI + d] = f2us((p + Dd*xv) * siluf(zv));
  }
}

extern "C" void kernel_launch(void* const* d_in, const int* in_sizes, int n_in,
                              void* d_out, int out_size, void* d_ws, size_t ws_size,
                              hipStream_t stream) {
  const float* hs         = (const float*)d_in[0];
  const float* in_proj_w  = (const float*)d_in[1];
  const float* conv_w     = (const float*)d_in[2];
  const float* conv_b     = (const float*)d_in[3];
  const float* x_proj_w   = (const float*)d_in[4];
  const float* dt_proj_w  = (const float*)d_in[5];
  const float* dt_proj_b  = (const float*)d_in[6];
  const float* dt_ln_w    = (const float*)d_in[7];
  const float* b_ln_w     = (const float*)d_in[8];
  const float* c_ln_w     = (const float*)d_in[9];
  const float* A_log      = (const float*)d_in[10];
  const float* D_skip     = (const float*)d_in[11];
  const float* out_proj_w = (const float*)d_in[12];
  const float* input_ln_w = (const float*)d_in[13];
  const float* pre_moe_ln = (const float*)d_in[14];
  const float* gate_w     = (const float*)d_in[15];
  const float* up_w       = (const float*)d_in[16];
  const float* down_w     = (const float*)d_in[17];
  float* outF = (float*)d_out;

  // ---- workspace (~89.5 MB with aliasing) ----
  char* p = (char*)d_ws;
  auto alloc = [&](size_t bytes) { void* r = (void*)p; p += (bytes + 255) & ~(size_t)255; return r; };
  ushort* WT_in   = (ushort*)alloc((size_t)4096*1024*2);
  ushort* WT_out  = (ushort*)alloc((size_t)1024*2048*2);
  ushort* WT_gate = (ushort*)alloc((size_t)4096*1024*2);
  ushort* WT_up   = (ushort*)alloc((size_t)4096*1024*2);
  ushort* WT_down = (ushort*)alloc((size_t)1024*4096*2);
  ushort* HN_bf   = (ushort*)alloc((size_t)S_*DM*2);
  ushort* XCbf    = (ushort*)alloc((size_t)S_*DI*2);
  ushort* ZY      = (ushort*)alloc((size_t)S_*DI*2);     // z, later y*silu(z)
  float*  XZx     = (float*) alloc((size_t)S_*DI*4);     // x pre-conv (steps 2-3b)
  float*  DT      = (float*) alloc((size_t)S_*DI*4);     // dt (step 6+)
  float*  PROJ    = (float*) alloc((size_t)S_*96*4);
  float*  NDT     = (float*) alloc((size_t)S_*DTR*4);
  float*  BC      = (float*) alloc((size_t)S_*32*4);
  // aliases (lifetime-disjoint):
  ushort* FFbf  = (ushort*)XZx;               // FFN act (steps 10-11)
  float*  PROJP = DT;                         // x_proj partials (4-4b); DT written at 6
  float*  SC_A  = XZx;                        // scan carries (7); XZx dead after 3b/4
  float*  SC_H  = SC_A + (size_t)DI*DSTATE*NC; // exactly fills XZx (16.78 MB)

  // ---- one-time weight convert+transpose to bf16 [N][K] ----
  k_wt<<<dim3(4096/32, 1024/32), 256, 0, stream>>>(in_proj_w,  WT_in,   1024, 4096);
  k_wt<<<dim3(1024/32, 2048/32), 256, 0, stream>>>(out_proj_w, WT_out,  2048, 1024);
  k_wt<<<dim3(4096/32, 1024/32), 256, 0, stream>>>(gate_w,     WT_gate, 1024, 4096);
  k_wt<<<dim3(4096/32, 1024/32), 256, 0, stream>>>(up_w,       WT_up,   1024, 4096);
  k_wt<<<dim3(1024/32, 4096/32), 256, 0, stream>>>(down_w,     WT_down, 4096, 1024);

  for (int b = 0; b < B_; ++b) {
    const float* hs_b  = hs   + (size_t)b*S_*DM;
    float*       out_b = outF + (size_t)b*S_*DM;   // HID (f32), then final out

    // 1. input RMSNorm -> bf16
    k_rms<<<S_, 256, 0, stream>>>(hs_b, input_ln_w, HN_bf);
    // 2. in_proj MFMA: x-half -> XZx f32, z-half -> ZY bf16
    k_mfma<0,128><<<dim3(32, 16), 256, 0, stream>>>(HN_bf, WT_in, nullptr, nullptr,
        XZx, ZY, nullptr, S_, 2*DI, DM);
    // 3. conv + silu -> XC bf16
    k_conv<<<(S_*DI)/256, 256, 0, stream>>>(XZx, conv_w, conv_b, XCbf);
    // 3b. conv_state (f32 path)
    k_convstate<<<(DI*KC)/256, 256, 0, stream>>>(XZx, outF, b);
    // 4. x_proj split-K -> partials; 4b. reduce -> PROJ
    k_xproj<<<dim3(KS, S_/64), 256, 0, stream>>>(XCbf, x_proj_w, PROJP);
    k_xred<<<(S_*96)/256, 256, 0, stream>>>(PROJP, PROJ);
    // 5. small RMSNorms
    k_norms<<<S_, 64, 0, stream>>>(PROJ, dt_ln_w, b_ln_w, c_ln_w, NDT, BC);
    // 6. dt projection + softplus -> DT f32
    k_dtproj<<<dim3(DI/256, S_/16), 256, 0, stream>>>(NDT, dt_proj_w, dt_proj_b, DT);
    // 7. chunked parallel scan (NC=64, thread-per-(d,chunk), h[16] in regs)
    k_scan1<<<(DI*NC)/256, 256, 0, stream>>>(DT, XCbf, BC, A_log, SC_A, SC_H);
    k_scan2<<<(DI*DSTATE)/256, 256, 0, stream>>>(SC_A, SC_H, outF, b);
    k_scan3<<<(DI*NC)/256, 256, 0, stream>>>(DT, XCbf, BC, A_log, D_skip, SC_A, ZY);
    // 8. out_proj MFMA + residual -> out_b (f32 HID)
    k_mfma<1,64><<<dim3(16, 16), 256, 0, stream>>>(ZY, WT_out, nullptr, hs_b,
        nullptr, nullptr, out_b, S_, DM, DI);
    // 9. pre-MoE RMSNorm -> bf16
    k_rms<<<S_, 256, 0, stream>>>(out_b, pre_moe_ln, HN_bf);
    // 10. gate/up dual MFMA -> FFbf (aliases XZx; scan carries dead)
    k_mfma<2,128><<<dim3(32, 16), 256, 0, stream>>>(HN_bf, WT_gate, WT_up, nullptr,
        nullptr, FFbf, nullptr, S_, DFF, DM);
    // 11. down MFMA + residual(out_b) -> out_b final
    k_mfma<1,64><<<dim3(16, 16), 256, 0, stream>>>(FFbf, WT_down, nullptr, out_b,
        nullptr, nullptr, out_b, S_, DM, DFF);
  }
}

// Round 7
// 681.716 us; speedup vs baseline: 7.5611x; 1.1844x over previous
//
#include <hip/hip_runtime.h>
#include <hip/hip_bf16.h>

#define B_ 2
#define S_ 2048
#define DM 1024
#define DI 2048
#define DSTATE 16
#define DTR 64
#define KC 4
#define DFF 4096
#define EPSF 1e-6f
#define T_ (B_*S_)
#define NC 32
#define LCH (S_/NC)
#define KS 16
#define KCH (DI/KS)

#define CONV_OFF (T_*DM)
#define SSM_OFF  (CONV_OFF + B_*DI*KC)

typedef __attribute__((ext_vector_type(8))) short short8;
typedef __attribute__((ext_vector_type(4))) float f32x4;

__device__ __forceinline__ float siluf(float x){ return x / (1.f + __expf(-x)); }
__device__ __forceinline__ float softplusf(float x){
  return (x > 0.f) ? (x + log1pf(__expf(-x))) : log1pf(__expf(x));
}
__device__ __forceinline__ float us2f(ushort u){
  union { float f; unsigned u32; } v; v.u32 = ((unsigned)u) << 16; return v.f;
}
__device__ __forceinline__ ushort f2us(float f){
  __hip_bfloat16 h = __float2bfloat16(f);
  return *reinterpret_cast<ushort*>(&h);
}
__device__ __forceinline__ void gld16(const ushort* g, ushort* l) {
  __builtin_amdgcn_global_load_lds(
      (const __attribute__((address_space(1))) void*)g,
      (__attribute__((address_space(3))) void*)l, 16, 0, 0);
}

// ---------------- weight convert+transpose: W f32 [K][N] -> WT bf16 [N][K] --------
__global__ __launch_bounds__(256) void k_wt(const float* __restrict__ W,
    ushort* __restrict__ WT, int K, int N) {
  __shared__ float t[32][33];
  int n0 = blockIdx.x * 32, k0 = blockIdx.y * 32;
  int tx = threadIdx.x & 31, ty = threadIdx.x >> 5;
  #pragma unroll
  for (int i = 0; i < 4; ++i) t[ty + i*8][tx] = W[(size_t)(k0 + ty + i*8)*N + n0 + tx];
  __syncthreads();
  #pragma unroll
  for (int i = 0; i < 4; ++i)
    WT[(size_t)(n0 + ty + i*8)*K + k0 + tx] = f2us(t[tx][ty + i*8]);
}

// ---------------- RMSNorm (D=1024), f32 in -> bf16 out ---------------------------
__global__ __launch_bounds__(256) void k_rms(const float* __restrict__ in,
    const float* __restrict__ w, ushort* __restrict__ out) {
  int t = blockIdx.x, tid = threadIdx.x;
  const size_t base = (size_t)t * DM;
  float v[4]; float ss = 0.f;
  #pragma unroll
  for (int i = 0; i < 4; ++i) {
    float x = in[base + tid + i*256];
    v[i] = x; ss += x * x;
  }
  #pragma unroll
  for (int m = 1; m < 64; m <<= 1) ss += __shfl_xor(ss, m, 64);
  __shared__ float sred[4];
  if ((tid & 63) == 0) sred[tid >> 6] = ss;
  __syncthreads();
  float tot = sred[0] + sred[1] + sred[2] + sred[3];
  float r = rsqrtf(tot * (1.f / DM) + EPSF);
  #pragma unroll
  for (int i = 0; i < 4; ++i)
    out[base + tid + i*256] = f2us(v[i] * r * w[tid + i*256]);
}

// ---------------- MFMA GEMM, m97-style: global_load_lds + st_16x32 swizzle -------
// MODE 0 (in_proj): gc<DI -> XP bf16 (x) ; gc>=DI -> outX bf16 (z)
// MODE 1 (add):     outF = acc + Res(f32)   [Res/outF may alias: no restrict]
// MODE 2 (gate/up): outU = bf16(silu(acc)*acc2)
template<int MODE, int BN>
__global__ __launch_bounds__(256) void k_mfma(
    const ushort* __restrict__ Ag, const ushort* __restrict__ B1,
    const ushort* __restrict__ B2, const float* Res,
    ushort* __restrict__ outU, ushort* __restrict__ outX,
    float* outF, int M, int N, int K)
{
  __shared__ __attribute__((aligned(16))) ushort As[128*32];
  __shared__ __attribute__((aligned(16))) ushort Bs[BN*32];
  __shared__ __attribute__((aligned(16))) ushort Bs2[(MODE==2)?BN*32:8];
  constexpr int NFM = (BN==128)?4:2;
  constexpr int BCH = BN*32*2/1024;
  int tid = threadIdx.x;
  int gn0 = blockIdx.x * BN, gm0 = blockIdx.y * 128;
  int wid = tid >> 6, lane = tid & 63;
  int mo = (BN==128) ? (wid>>1)*64 : wid*32;
  int no = (BN==128) ? (wid&1)*64 : 0;
  int lr = lane & 15, lk = lane >> 4;
  int srow = lane >> 2;
  int scol = ((lane & 3) * 8) ^ ((lane & 32) ? 16 : 0);

  f32x4 acc[NFM][4];
  f32x4 acc2[(MODE==2)?NFM:1][(MODE==2)?4:1];
  #pragma unroll
  for (int i = 0; i < NFM; ++i)
    #pragma unroll
    for (int j = 0; j < 4; ++j) {
      acc[i][j] = (f32x4){0.f,0.f,0.f,0.f};
      if (MODE == 2) acc2[i][j] = (f32x4){0.f,0.f,0.f,0.f};
    }

  for (int k0 = 0; k0 < K; k0 += 32) {
    for (int ch = wid; ch < 8; ch += 4)
      gld16(Ag + (size_t)(gm0 + ch*16 + srow)*K + k0 + scol, &As[ch*512]);
    for (int ch = wid; ch < BCH; ch += 4)
      gld16(B1 + (size_t)(gn0 + ch*16 + srow)*K + k0 + scol, &Bs[ch*512]);
    if (MODE == 2)
      for (int ch = wid; ch < BCH; ch += 4)
        gld16(B2 + (size_t)(gn0 + ch*16 + srow)*K + k0 + scol, &Bs2[ch*512]);
    __syncthreads();
    int rcsw = (lr & 8) ? 16 : 0;
    short8 af[NFM], bfr[4], bfr2[(MODE==2)?4:1];
    #pragma unroll
    for (int mi = 0; mi < NFM; ++mi)
      af[mi] = *(const short8*)&As[(mo + mi*16 + lr)*32 + (lk*8 ^ rcsw)];
    #pragma unroll
    for (int ni = 0; ni < 4; ++ni) {
      bfr[ni] = *(const short8*)&Bs[(no + ni*16 + lr)*32 + (lk*8 ^ rcsw)];
      if (MODE == 2) bfr2[ni] = *(const short8*)&Bs2[(no + ni*16 + lr)*32 + (lk*8 ^ rcsw)];
    }
    #pragma unroll
    for (int mi = 0; mi < NFM; ++mi)
      #pragma unroll
      for (int ni = 0; ni < 4; ++ni) {
        acc[mi][ni] = __builtin_amdgcn_mfma_f32_16x16x32_bf16(af[mi], bfr[ni], acc[mi][ni], 0, 0, 0);
        if (MODE == 2)
          acc2[mi][ni] = __builtin_amdgcn_mfma_f32_16x16x32_bf16(af[mi], bfr2[ni], acc2[mi][ni], 0, 0, 0);
      }
    __syncthreads();
  }

  #pragma unroll
  for (int mi = 0; mi < NFM; ++mi)
    #pragma unroll
    for (int ni = 0; ni < 4; ++ni)
      #pragma unroll
      for (int r = 0; r < 4; ++r) {
        int gr = gm0 + mo + mi*16 + lk*4 + r;
        int gc = gn0 + no + ni*16 + lr;
        float v = acc[mi][ni][r];
        size_t idx = (size_t)gr*N + gc;
        if (MODE == 0) {
          if (gc < DI) outU[(size_t)gr*DI + gc] = f2us(v);
          else         outX[(size_t)gr*DI + gc - DI] = f2us(v);
        } else if (MODE == 1) {
          outF[idx] = v + Res[idx];
        } else {
          outU[idx] = f2us(siluf(v) * acc2[mi][ni][r]);
        }
      }
}

// ---------------- x_proj split-K: XC bf16 [T][DI] * B f32 [DI][96] -> partials ----
__global__ __launch_bounds__(256) void k_xproj(const ushort* __restrict__ A,
    const float* __restrict__ Bw, float* __restrict__ PP) {
  __shared__ float As[16][65];
  __shared__ float Bsh[16][96];
  int tid = threadIdx.x;
  int ks = blockIdx.x, mt = blockIdx.y;
  int m0 = mt*64, k0 = ks*KCH;
  int r0 = (tid >> 4) * 4, c0 = (tid & 15) * 6;
  float acc[4][6] = {};
  for (int kk0 = 0; kk0 < KCH; kk0 += 16) {
    #pragma unroll
    for (int i = 0; i < 4; ++i) {
      int e = tid + i*256;
      As[e & 15][e >> 4] = us2f(A[(size_t)(m0 + (e >> 4))*DI + k0 + kk0 + (e & 15)]);
    }
    #pragma unroll
    for (int i = 0; i < 6; ++i) {
      int e = tid + i*256;
      int kk = e / 96, c = e - kk*96;
      Bsh[kk][c] = Bw[(size_t)(k0 + kk0 + kk)*96 + c];
    }
    __syncthreads();
    #pragma unroll
    for (int kk = 0; kk < 16; ++kk) {
      float a[4], bv[6];
      #pragma unroll
      for (int i = 0; i < 4; ++i) a[i] = As[kk][r0 + i];
      #pragma unroll
      for (int j = 0; j < 6; ++j) bv[j] = Bsh[kk][c0 + j];
      #pragma unroll
      for (int i = 0; i < 4; ++i)
        #pragma unroll
        for (int j = 0; j < 6; ++j) acc[i][j] += a[i] * bv[j];
    }
    __syncthreads();
  }
  float* dst = PP + (size_t)ks*T_*96;
  #pragma unroll
  for (int i = 0; i < 4; ++i)
    #pragma unroll
    for (int j = 0; j < 6; ++j)
      dst[(size_t)(m0 + r0 + i)*96 + c0 + j] = acc[i][j];
}

// ---------------- fused xred + small RMSNorms: partials -> NDT, BC ---------------
__global__ __launch_bounds__(128) void k_xrednorms(const float* __restrict__ PP,
    const float* __restrict__ dtw, const float* __restrict__ bw,
    const float* __restrict__ cw, float* __restrict__ NDT,
    float* __restrict__ BC) {
  int t = blockIdx.x, tid = threadIdx.x;
  __shared__ float pr[96];
  if (tid < 96) {
    float s = 0.f;
    #pragma unroll
    for (int ks = 0; ks < KS; ++ks) s += PP[((size_t)ks*T_ + t)*96 + tid];
    pr[tid] = s;
  }
  __syncthreads();
  if (tid < 64) {
    float v = pr[tid];
    float ss = v * v;
    #pragma unroll
    for (int m = 1; m < 64; m <<= 1) ss += __shfl_xor(ss, m, 64);
    float r = rsqrtf(ss * (1.f / DTR) + EPSF);
    NDT[(size_t)t*DTR + tid] = v * r * dtw[tid];
  } else if (tid < 96) {
    int l = tid - 64;                      // wave-1 lanes 0..31
    float u = pr[64 + l];
    float s2 = u * u;
    #pragma unroll
    for (int m = 1; m < 16; m <<= 1) s2 += __shfl_xor(s2, m, 16);
    float r2 = rsqrtf(s2 * (1.f / DSTATE) + EPSF);
    float wv = (l < 16) ? bw[l] : cw[l - 16];
    BC[(size_t)t*32 + l] = u * r2 * wv;
  }
}

// ---------------- depthwise causal conv + bias + silu + conv_state ---------------
__global__ __launch_bounds__(256) void k_conv(const ushort* __restrict__ XP,
    const float* __restrict__ cw, const float* __restrict__ cb,
    ushort* __restrict__ XC, float* __restrict__ outF) {
  int i = blockIdx.x * 256 + threadIdx.x;   // row*DI + d, row < T_
  int d = i & (DI - 1);
  int row = i >> 11;
  int s = row & (S_ - 1);
  int b = row >> 11;
  float acc = cb[d];
  float xlast = 0.f;
  #pragma unroll
  for (int k = 0; k < KC; ++k) {
    int s2 = s - (KC - 1) + k;
    if (s2 >= 0) {
      float xv = us2f(XP[(size_t)(row - (s - s2))*DI + d]);
      acc += xv * cw[d*KC + k];
      xlast = xv;
    }
  }
  XC[i] = f2us(siluf(acc));
  if (s >= S_ - KC)
    outF[CONV_OFF + b*DI*KC + d*KC + (s - (S_ - KC))] = xlast;
}

// ---------------- dt projection: (T x 64) @ (64 x DI) + bias, softplus -> f32 ----
__global__ __launch_bounds__(256) void k_dtproj(const float* __restrict__ NDT,
    const float* __restrict__ W, const float* __restrict__ bias,
    float* __restrict__ DT) {
  __shared__ float nd[16][64];
  int tid = threadIdx.x;
  int d = blockIdx.x * 256 + tid;
  int t0 = blockIdx.y * 16;
  #pragma unroll
  for (int i = 0; i < 4; ++i) {
    int idx = tid + i*256;
    nd[idx >> 6][idx & 63] = NDT[(size_t)(t0 + (idx >> 6))*DTR + (idx & 63)];
  }
  __syncthreads();
  float acc[16] = {};
  for (int k = 0; k < 64; ++k) {
    float wv = W[(size_t)k*DI + d];
    #pragma unroll
    for (int tk = 0; tk < 16; ++tk) acc[tk] += nd[tk][k] * wv;
  }
  float bv = bias[d];
  #pragma unroll
  for (int tk = 0; tk < 16; ++tk)
    DT[(size_t)(t0 + tk)*DI + d] = softplusf(acc[tk] + bv);
}

// ---------------- scan phase 1: thread per (b,c,d); h[16] in regs ----------------
__global__ __launch_bounds__(256) void k_scan1(const float* __restrict__ DT,
    const ushort* __restrict__ XC, const float* __restrict__ BC,
    const float* __restrict__ A_log, float* __restrict__ scA,
    float* __restrict__ scH) {
  int g = blockIdx.x * 256 + threadIdx.x;   // b*(NC*DI) + c*DI + d
  int d = g & (DI - 1);
  int c = (g >> 11) & (NC - 1);
  int b = g >> 16;
  float A[16], h[16], ap[16];
  #pragma unroll
  for (int q = 0; q < 4; ++q) {
    f32x4 al = *(const f32x4*)(A_log + d*DSTATE + q*4);
    #pragma unroll
    for (int r = 0; r < 4; ++r) {
      A[q*4+r] = -__expf(al[r]);
      h[q*4+r] = 0.f; ap[q*4+r] = 1.f;
    }
  }
  int trow0 = b*S_ + c*LCH;
  for (int i = 0; i < LCH; ++i) {
    int t = trow0 + i;
    float dtv = DT[(size_t)t*DI + d];
    float dtx = dtv * us2f(XC[(size_t)t*DI + d]);
    const f32x4* bc = (const f32x4*)(BC + (size_t)t*32);
    #pragma unroll
    for (int q = 0; q < 4; ++q) {
      f32x4 Bv = bc[q];
      #pragma unroll
      for (int r = 0; r < 4; ++r) {
        int n = q*4+r;
        float dA = __expf(dtv * A[n]);
        h[n] = h[n]*dA + dtx*Bv[r];
        ap[n] *= dA;
      }
    }
  }
  size_t base = ((size_t)(b*NC + c)*DI + d)*DSTATE;
  #pragma unroll
  for (int q = 0; q < 4; ++q) {
    *(f32x4*)(scA + base + q*4) = (f32x4){ap[q*4],ap[q*4+1],ap[q*4+2],ap[q*4+3]};
    *(f32x4*)(scH + base + q*4) = (f32x4){h[q*4],h[q*4+1],h[q*4+2],h[q*4+3]};
  }
}

// ---------------- scan phase 2: combine; h_start in place over scA; ssm_state ----
__global__ __launch_bounds__(256) void k_scan2(float* scAS,
    const float* __restrict__ scH, float* __restrict__ outF) {
  int g = blockIdx.x * 256 + threadIdx.x;   // b*32768 + dn
  int b = g >> 15;
  int dn = g & (DI*DSTATE - 1);
  float h = 0.f;
  #pragma unroll 4
  for (int c = 0; c < NC; ++c) {
    size_t idx = (size_t)(b*NC + c)*DI*DSTATE + dn;
    float a = scAS[idx];
    float hh = scH[idx];
    scAS[idx] = h;
    h = a*h + hh;
  }
  outF[SSM_OFF + (size_t)b*DI*DSTATE + dn] = h;
}

// ---------------- scan phase 3: replay; in-reg C-dot; fused y*silu(z) ------------
__global__ __launch_bounds__(256) void k_scan3(const float* __restrict__ DT,
    const ushort* __restrict__ XC, const float* __restrict__ BC,
    const float* __restrict__ A_log, const float* __restrict__ Dskip,
    const float* __restrict__ scS, ushort* ZY) {
  int g = blockIdx.x * 256 + threadIdx.x;
  int d = g & (DI - 1);
  int c = (g >> 11) & (NC - 1);
  int b = g >> 16;
  float A[16], h[16];
  size_t base = ((size_t)(b*NC + c)*DI + d)*DSTATE;
  #pragma unroll
  for (int q = 0; q < 4; ++q) {
    f32x4 al = *(const f32x4*)(A_log + d*DSTATE + q*4);
    f32x4 h0 = *(const f32x4*)(scS + base + q*4);
    #pragma unroll
    for (int r = 0; r < 4; ++r) {
      A[q*4+r] = -__expf(al[r]);
      h[q*4+r] = h0[r];
    }
  }
  float Dd = Dskip[d];
  int trow0 = b*S_ + c*LCH;
  for (int i = 0; i < LCH; ++i) {
    int t = trow0 + i;
    float dtv = DT[(size_t)t*DI + d];
    float xv  = us2f(XC[(size_t)t*DI + d]);
    float dtx = dtv * xv;
    const f32x4* bc = (const f32x4*)(BC + (size_t)t*32);
    float p = 0.f;
    #pragma unroll
    for (int q = 0; q < 4; ++q) {
      f32x4 Bv = bc[q];
      f32x4 Cv = bc[4+q];
      #pragma unroll
      for (int r = 0; r < 4; ++r) {
        int n = q*4+r;
        float dA = __expf(dtv * A[n]);
        h[n] = h[n]*dA + dtx*Bv[r];
        p += h[n]*Cv[r];
      }
    }
    float zv = us2f(ZY[(size_t)t*DI + d]);
    ZY[(size_t)t*DI + d] = f2us((p + Dd*xv) * siluf(zv));
  }
}

extern "C" void kernel_launch(void* const* d_in, const int* in_sizes, int n_in,
                              void* d_out, int out_size, void* d_ws, size_t ws_size,
                              hipStream_t stream) {
  const float* hs         = (const float*)d_in[0];
  const float* in_proj_w  = (const float*)d_in[1];
  const float* conv_w     = (const float*)d_in[2];
  const float* conv_b     = (const float*)d_in[3];
  const float* x_proj_w   = (const float*)d_in[4];
  const float* dt_proj_w  = (const float*)d_in[5];
  const float* dt_proj_b  = (const float*)d_in[6];
  const float* dt_ln_w    = (const float*)d_in[7];
  const float* b_ln_w     = (const float*)d_in[8];
  const float* c_ln_w     = (const float*)d_in[9];
  const float* A_log      = (const float*)d_in[10];
  const float* D_skip     = (const float*)d_in[11];
  const float* out_proj_w = (const float*)d_in[12];
  const float* input_ln_w = (const float*)d_in[13];
  const float* pre_moe_ln = (const float*)d_in[14];
  const float* gate_w     = (const float*)d_in[15];
  const float* up_w       = (const float*)d_in[16];
  const float* down_w     = (const float*)d_in[17];
  float* outF = (float*)d_out;

  // ---- workspace, batch-fused (~123 MB peak) ----
  char* p = (char*)d_ws;
  auto alloc = [&](size_t bytes) { void* r = (void*)p; p += (bytes + 255) & ~(size_t)255; return r; };
  ushort* WT_in   = (ushort*)alloc((size_t)4096*1024*2);
  ushort* WT_out  = (ushort*)alloc((size_t)1024*2048*2);
  ushort* WT_gate = (ushort*)alloc((size_t)4096*1024*2);
  ushort* WT_up   = (ushort*)alloc((size_t)4096*1024*2);
  ushort* WT_down = (ushort*)alloc((size_t)1024*4096*2);
  ushort* XC      = (ushort*)alloc((size_t)T_*DI*2);     // conv output
  ushort* ZY      = (ushort*)alloc((size_t)T_*DI*2);     // z, then y*silu(z)
  void*   R1      = alloc((size_t)B_*NC*DI*DSTATE*4*2);  // 16.78 MB: XP / carries
  void*   R2      = alloc((size_t)T_*DI*4);              // 33.55 MB: HN/PROJP/DT/HN
  float*  NDT     = (float*)alloc((size_t)T_*DTR*4);
  float*  BC      = (float*)alloc((size_t)T_*32*4);
  // time-shared views:
  ushort* XP    = (ushort*)R1;                          // x pre-conv (steps 2-3)
  float*  SC_A  = (float*)R1;                           // carries (step 7)
  float*  SC_H  = SC_A + (size_t)B_*NC*DI*DSTATE;
  ushort* HN    = (ushort*)R2;                          // rms out (1-2, 9-10)
  float*  PROJP = (float*)R2;                           // x_proj partials (4)
  float*  DT    = (float*)R2;                           // dt (6-7)
  ushort* FF    = XC;                                   // FFN act spans XC+ZY (10-11)

  // ---- one-time weight convert+transpose to bf16 [N][K] ----
  k_wt<<<dim3(4096/32, 1024/32), 256, 0, stream>>>(in_proj_w,  WT_in,   1024, 4096);
  k_wt<<<dim3(1024/32, 2048/32), 256, 0, stream>>>(out_proj_w, WT_out,  2048, 1024);
  k_wt<<<dim3(4096/32, 1024/32), 256, 0, stream>>>(gate_w,     WT_gate, 1024, 4096);
  k_wt<<<dim3(4096/32, 1024/32), 256, 0, stream>>>(up_w,       WT_up,   1024, 4096);
  k_wt<<<dim3(1024/32, 4096/32), 256, 0, stream>>>(down_w,     WT_down, 4096, 1024);

  // 1. input RMSNorm (both batches) -> HN bf16
  k_rms<<<T_, 256, 0, stream>>>(hs, input_ln_w, HN);
  // 2. in_proj MFMA: x -> XP bf16, z -> ZY bf16
  k_mfma<0,128><<<dim3(32, 32), 256, 0, stream>>>(HN, WT_in, nullptr, nullptr,
      XP, ZY, nullptr, T_, 2*DI, DM);
  // 3. conv + silu -> XC; conv_state -> out
  k_conv<<<(T_*DI)/256, 256, 0, stream>>>(XP, conv_w, conv_b, XC, outF);
  // 4. x_proj split-K -> partials (R2)
  k_xproj<<<dim3(KS, T_/64), 256, 0, stream>>>(XC, x_proj_w, PROJP);
  // 4b+5. fused reduce + small RMSNorms -> NDT, BC
  k_xrednorms<<<T_, 128, 0, stream>>>(PROJP, dt_ln_w, b_ln_w, c_ln_w, NDT, BC);
  // 6. dt projection + softplus -> DT (R2, over partials)
  k_dtproj<<<dim3(DI/256, T_/16), 256, 0, stream>>>(NDT, dt_proj_w, dt_proj_b, DT);
  // 7. chunked parallel scan, both batches (carries in R1 over XP)
  k_scan1<<<(B_*NC*DI)/256, 256, 0, stream>>>(DT, XC, BC, A_log, SC_A, SC_H);
  k_scan2<<<(B_*DI*DSTATE)/256, 256, 0, stream>>>(SC_A, SC_H, outF);
  k_scan3<<<(B_*NC*DI)/256, 256, 0, stream>>>(DT, XC, BC, A_log, D_skip, SC_A, ZY);
  // 8. out_proj MFMA + residual(hs) -> outF[0:T*DM] (f32 HID)
  k_mfma<1,64><<<dim3(16, 32), 256, 0, stream>>>(ZY, WT_out, nullptr, hs,
      nullptr, nullptr, outF, T_, DM, DI);
  // 9. pre-MoE RMSNorm -> HN (R2; DT dead)
  k_rms<<<T_, 256, 0, stream>>>(outF, pre_moe_ln, HN);
  // 10. gate/up dual MFMA -> FF bf16 (spans XC+ZY, both dead)
  k_mfma<2,128><<<dim3(32, 32), 256, 0, stream>>>(HN, WT_gate, WT_up, nullptr,
      FF, nullptr, nullptr, T_, DFF, DM);
  // 11. down MFMA + residual(outF) -> outF final
  k_mfma<1,64><<<dim3(16, 32), 256, 0, stream>>>(FF, WT_down, nullptr, outF,
      nullptr, nullptr, outF, T_, DM, DFF);
}